// Round 16
// baseline (1990.272 us; speedup 1.0000x reference)
//
#include <hip/hip_runtime.h>
#include <math.h>

#define VOCAB 32000
#define D 256
#define NB 32
#define NEQ 5
#define SEQ 64
#define NBASIS 96   // 32 bubbles + 64 token vectors

// ws layout (float offsets)
#define WS_S     0                          // [96][96] Gram of basis U=[B;X]
#define WS_COEF  (NBASIS*NBASIS)            // [SEQ][96] x_wm coefficients
#define WS_U     (WS_COEF + SEQ*NBASIS)     // [SEQ][NB]
#define WS_VV    (WS_U + SEQ*NB)            // [SEQ][NB]  (must stay right after WS_U)
#define WS_C     (WS_VV + SEQ*NB)           // [SEQ]
#define WS_WHL   (WS_C + SEQ)               // ushort[2][96][256]: basis hi plane, lo plane
#define WS_FLAG  (WS_WHL + NBASIS*D)        // unsigned scan-done flag (1 elem)

typedef __attribute__((ext_vector_type(8))) short short8v;
typedef __attribute__((ext_vector_type(4))) float f32x4;

// ---------------------------------------------------------------------------
// Fast cross-lane / math primitives
// ---------------------------------------------------------------------------
template <int CTRL>
__device__ __forceinline__ float dpp_add(float x) {
    int yi = __builtin_amdgcn_update_dpp(0, __float_as_int(x), CTRL, 0xF, 0xF, true);
    return x + __int_as_float(yi);
}
__device__ __forceinline__ float xor16_add(float x) {
    float a, b;
    asm("v_mov_b32 %0, %2\n\t"
        "v_mov_b32 %1, %2\n\t"
        "v_permlane16_swap_b32 %0, %1"
        : "=&v"(a), "=&v"(b) : "v"(x));
    return a + b;
}
__device__ __forceinline__ float xor32_add(float x) {
    float a, b;
    asm("v_mov_b32 %0, %2\n\t"
        "v_mov_b32 %1, %2\n\t"
        "v_permlane32_swap_b32 %0, %1"
        : "=&v"(a), "=&v"(b) : "v"(x));
    return a + b;
}
__device__ __forceinline__ float sum32h(float x) {
    x = dpp_add<0xB1>(x);    // xor 1
    x = dpp_add<0x4E>(x);    // xor 2
    x = dpp_add<0x124>(x);   // row_ror:4
    x = dpp_add<0x128>(x);   // row_ror:8
    return xor16_add(x);
}
__device__ __forceinline__ float sum64(float x) {
    return xor32_add(sum32h(x));
}
__device__ __forceinline__ float rdlane(float v, int lane) {
    return __int_as_float(__builtin_amdgcn_readlane(__float_as_int(v), lane));
}
__device__ __forceinline__ float fast_rcp(float x) {
    float r; asm("v_rcp_f32 %0, %1" : "=v"(r) : "v"(x)); return r;
}
__device__ __forceinline__ float fast_rsq(float x) {
    float r; asm("v_rsq_f32 %0, %1" : "=v"(r) : "v"(x)); return r;
}
__device__ __forceinline__ float fast_exp2(float x) {
    float r; asm("v_exp_f32 %0, %1" : "=v"(r) : "v"(x)); return r;
}
__device__ __forceinline__ void split1(float x, short& hi, short& lo) {
    unsigned xb = __builtin_bit_cast(unsigned, x);
    unsigned hb = xb & 0xFFFF0000u;
    float fl = x - __builtin_bit_cast(float, hb);
    hi = (short)(hb >> 16);
    lo = (short)(__builtin_bit_cast(unsigned, fl) >> 16);
}
// split 8 f32 (from memory) -> bf16 hi/lo fragments
__device__ __forceinline__ void split_bf16(const float* p, short8v& hi, short8v& lo) {
    float4 f0 = *(const float4*)p;
    float4 f1 = *(const float4*)(p + 4);
    float f[8] = {f0.x, f0.y, f0.z, f0.w, f1.x, f1.y, f1.z, f1.w};
    #pragma unroll
    for (int j = 0; j < 8; ++j) { short h, l; split1(f[j], h, l); hi[j] = h; lo[j] = l; }
}
// split 8 f32 (register array) -> bf16 hi/lo fragments
__device__ __forceinline__ void split8r(const float* f, short8v& hi, short8v& lo) {
    #pragma unroll
    for (int j = 0; j < 8; ++j) { short h, l; split1(f[j], h, l); hi[j] = h; lo[j] = l; }
}

// ---------------------------------------------------------------------------
// K1: Gram matrix + U bf16 hi/lo planes (U = [bubbles; E[tokens]]). Also
// resets the scan-done flag (graph-replay determinism).
// ---------------------------------------------------------------------------
__global__ __launch_bounds__(256) void foam_prep(
    const int* __restrict__ tokens, const float* __restrict__ E,
    const float* __restrict__ bubbles, float* __restrict__ ws)
{
    const int bid = blockIdx.x;    // basis row 0..95
    const int d = threadIdx.x;

    if (bid == 0 && d == 0) ((unsigned*)(ws + WS_FLAG))[0] = 0u;

    {
        const float val = (bid < NB) ? bubbles[bid * D + d]
                                     : E[(long)tokens[bid - NB] * D + d];
        short hi, lo;
        split1(val, hi, lo);
        unsigned short* Uhl = (unsigned short*)(ws + WS_WHL);
        Uhl[bid * D + d]              = (unsigned short)hi;
        Uhl[NBASIS * D + bid * D + d] = (unsigned short)lo;
    }

    const int idx = bid * 256 + d;
    if (idx < NBASIS * NBASIS) {
        const int i = idx / NBASIS, j = idx % NBASIS;
        const float4* ra = (const float4*)((i < NB) ? (bubbles + i * D)
                                                    : (E + (long)tokens[i - NB] * D));
        const float4* rb = (const float4*)((j < NB) ? (bubbles + j * D)
                                                    : (E + (long)tokens[j - NB] * D));
        float a0 = 0.f, a1 = 0.f, a2 = 0.f, a3 = 0.f;
        #pragma unroll
        for (int k = 0; k < D / 4; k += 4) {
            float4 x, y;
            x = ra[k];     y = rb[k];
            a0 = fmaf(x.x, y.x, fmaf(x.y, y.y, fmaf(x.z, y.z, fmaf(x.w, y.w, a0))));
            x = ra[k + 1]; y = rb[k + 1];
            a1 = fmaf(x.x, y.x, fmaf(x.y, y.y, fmaf(x.z, y.z, fmaf(x.w, y.w, a1))));
            x = ra[k + 2]; y = rb[k + 2];
            a2 = fmaf(x.x, y.x, fmaf(x.y, y.y, fmaf(x.z, y.z, fmaf(x.w, y.w, a2))));
            x = ra[k + 3]; y = rb[k + 3];
            a3 = fmaf(x.x, y.x, fmaf(x.y, y.y, fmaf(x.z, y.z, fmaf(x.w, y.w, a3))));
        }
        ws[WS_S + i * NBASIS + j] = (a0 + a1) + (a2 + a3);
    }
}

// ---------------------------------------------------------------------------
// KF: fully fused. Block 0 = serial scan -> release flag.
// Blocks 1..1000: GEMM Hf-tile (E@U^T) -> LDS, spin on flag (agent acquire),
// then in-block MFMA epilogue -> out. Hf never touches global memory.
// Co-residency guarantee: 1001 blocks <= 4/CU x 256 CUs (LDS 33792 B,
// 512 thr, launch_bounds(512,8)) -> no dispatch-order assumption needed.
// ---------------------------------------------------------------------------
#define MROWS 32
#define AS 264    // LDS A row stride in bf16 elems
#define HS 100    // LDS H row stride in floats

__global__ __launch_bounds__(512, 8) void foam_fused(
    const float* __restrict__ E,
    const float* __restrict__ p_mdb, const float* __restrict__ p_ns,
    float* __restrict__ ws, float* __restrict__ out)
{
    __shared__ __align__(16) char smem[MROWS * AS * 2 * 2];   // 33792 B
    const int tid = threadIdx.x;

    if (blockIdx.x == 0) {
        // ================= scan (verified body, unchanged) =================
        float (*S2)[NBASIS] = (float (*)[NBASIS])smem;
        const int l = tid;
        const int b = l & 31;
        const float* wsS = ws + WS_S;

        for (int e = l; e < SEQ * NBASIS / 4; e += 64)
            ((float4*)S2)[e] = ((const float4*)(wsS + NB * NBASIS))[e];

        float gbb_row[NB];
        {
            const float4* pa = (const float4*)(wsS + b * NBASIS);
            #pragma unroll
            for (int i = 0; i < 8; ++i) {
                float4 va = pa[i];
                gbb_row[4*i] = va.x; gbb_row[4*i+1] = va.y;
                gbb_row[4*i+2] = va.z; gbb_row[4*i+3] = va.w;
            }
        }
        const float diag = wsS[(NB + (l & 63)) * NBASIS + NB + (l & 63)];
        const float bn2  = wsS[b * NBASIS + b];

        const float LOG2E = 1.44269504088896f;
        const float mdb2  = p_mdb[0] * LOG2E;
        const float sens2 = fabsf(p_ns[0]) * LOG2E;
        const float sl2e  = 0.0625f * LOG2E;

        __syncthreads();
        if (l >= 64) return;

        float y = 0.f, mm2 = 0.f;
        float m1 = 0.f, m2 = 0.f;

        float* wsCOEF = ws + WS_COEF;
        float* wsUV   = ws + WS_U;
        float* wsC    = ws + WS_C;

        float gxcol = S2[0][b];
        float xcol1 = S2[0][l];
        float xcol2 = S2[0][32 + l];

        const int uvoff = (l >> 5) * (SEQ * NB);

        #pragma unroll 4
        for (int t = 0; t < SEQ; ++t) {
            const float xdm = sum64(fmaf(xcol2, m2, xcol1 * m1));
            const float px  = rdlane(diag, t);
            const float nov = (mm2 > 9.8e-17f)
                            ? (1.f - xdm * fast_rsq(px * mm2))
                            : 1.f;
            const float decay = fast_rcp(1.f + fast_exp2(fmaf(sens2, nov, -mdb2)));
            const float omd = 1.f - decay;

            wsCOEF[t * NBASIS + l] = fmaf(decay, m1, (l == NB + t) ? 1.f : 0.f);
            if (l >= 32)
                wsCOEF[t * NBASIS + 32 + l] = fmaf(decay, m2, (l == t) ? 1.f : 0.f);

            const float q = px + 2.f * decay * xdm + decay * decay * mm2;
            const float c = fmaf(decay, y, gxcol);

            const int tn = (t + 1) & (SEQ - 1);
            const float gxn = S2[tn][b];
            const float xn1 = S2[tn][l];
            const float xn2 = S2[tn][32 + l];

            const float cq2 = (c - q) * sl2e;
            float alpha = 1.f, p = 0.f;
            #pragma unroll
            for (int k = 0; k <= NEQ; ++k) {
                const float ev = fast_exp2(alpha * cq2);
                const float sm = sum32h(ev);
                const float r  = fast_rcp(sm);
                if (k < NEQ) {
                    const float ae = alpha * ev;
                    alpha = fmaf(-ae, r, alpha);
                } else {
                    p = ev * r;
                }
            }

            const float oma = 1.f - alpha;
            const float s2v = alpha * alpha * bn2 + 2.f * alpha * oma * c + oma * oma * q;
            const float g = p * fast_rcp(s2v + 1e-20f);
            const float uu  = g * alpha * alpha;
            const float vv2 = 2.f * g * alpha * oma;
            wsUV[uvoff + t * NB + b] = (l < NB) ? uu : vv2;

            float asg[NB];
            #pragma unroll
            for (int j = 0; j < NB; ++j) asg[j] = rdlane(alpha, j);
            float ga0 = 0.f, ga1 = 0.f, ga2 = 0.f, ga3 = 0.f;
            #pragma unroll
            for (int j = 0; j < NB; j += 4) {
                ga0 = fmaf(gbb_row[j],     asg[j],     ga0);
                ga1 = fmaf(gbb_row[j + 1], asg[j + 1], ga1);
                ga2 = fmaf(gbb_row[j + 2], asg[j + 2], ga2);
                ga3 = fmaf(gbb_row[j + 3], asg[j + 3], ga3);
            }
            const float ga = (ga0 + ga1) + (ga2 + ga3);

            const float r0 = sum32h(alpha);
            const float r1 = sum32h(alpha * c);
            const float r2 = sum32h(alpha * y);
            const float r3 = sum32h(alpha * ga);
            const float Cp = sum32h(g * oma * oma);
            if (l == 0) wsC[t] = Cp;

            const float msc = (32.f - r0) * (1.f / 32.f);
            const float k1 = decay * fmaf(omd, msc, 1.f);
            const float mmxwm = fmaf(decay, mm2, xdm);
            const float mmms = fmaf(msc, mmxwm, r2 * (1.f / 32.f));
            const float u1sq = r3 * (1.f / 1024.f);
            const float msms = fmaf(msc * msc, q, fmaf(2.f * msc, r1 * (1.f / 32.f), u1sq));
            mm2 = decay * decay * mm2 + 2.f * decay * omd * mmms + omd * omd * msms;

            y = fmaf(k1, y, omd * fmaf(msc, gxcol, ga * (1.f / 32.f)));

            const float inc1 = (l < NB) ? omd * alpha * (1.f / 32.f)
                                        : ((l == NB + t) ? omd * msc : 0.f);
            m1 = fmaf(k1, m1, inc1);
            m2 = fmaf(k1, m2, (t >= NB && l == t) ? omd * msc : 0.f);

            gxcol = gxn;
            xcol1 = xn1;
            xcol2 = xn2;
        }

        // publish scan results (device-scope release)
        if (l == 0)
            __hip_atomic_store((unsigned*)(ws + WS_FLAG), 1u,
                               __ATOMIC_RELEASE, __HIP_MEMORY_SCOPE_AGENT);
        return;
    }

    // ================= GEMM blocks: Hf tile = E @ U^T -> LDS =============
    short* Ah = (short*)smem;
    short* Al = Ah + MROWS * AS;

    const int w = tid >> 6;
    const int l = tid & 63;
    const int lm = l & 15;
    const int lq = l >> 4;

    const long vb = (long)(blockIdx.x - 1) * MROWS;

    {
        const float* src = E + vb * D;
        const int base = tid * 16;
        const int row = base >> 8;
        const int col = base & 255;
        float4 v0 = *(const float4*)(src + base);
        float4 v1 = *(const float4*)(src + base + 4);
        float4 v2 = *(const float4*)(src + base + 8);
        float4 v3 = *(const float4*)(src + base + 12);
        float f[16] = {v0.x,v0.y,v0.z,v0.w, v1.x,v1.y,v1.z,v1.w,
                       v2.x,v2.y,v2.z,v2.w, v3.x,v3.y,v3.z,v3.w};
        short8v h0, h1, l0, l1;
        #pragma unroll
        for (int j = 0; j < 8; ++j) { short hi, lo; split1(f[j], hi, lo); h0[j] = hi; l0[j] = lo; }
        #pragma unroll
        for (int j = 0; j < 8; ++j) { short hi, lo; split1(f[8+j], hi, lo); h1[j] = hi; l1[j] = lo; }
        *(short8v*)&Ah[row * AS + col]     = h0;
        *(short8v*)&Ah[row * AS + col + 8] = h1;
        *(short8v*)&Al[row * AS + col]     = l0;
        *(short8v*)&Al[row * AS + col + 8] = l1;
    }
    __syncthreads();

    f32x4 acc0 = {0.f,0.f,0.f,0.f}, acc1 = {0.f,0.f,0.f,0.f};
    if (w < 6) {
        const int n = w * 16 + lm;
        const short* bh = (const short*)(ws + WS_WHL) + n * D + lq * 8;
        const short* bl = bh + NBASIS * D;
        const short* ar = &Ah[lm * AS + lq * 8];
        const short* al = &Al[lm * AS + lq * 8];

        #pragma unroll
        for (int ks = 0; ks < 8; ++ks) {
            const short8v bhi = *(const short8v*)(bh + ks * 32);
            const short8v blo = *(const short8v*)(bl + ks * 32);

            short8v ahi = *(const short8v*)(ar + ks * 32);
            short8v alo = *(const short8v*)(al + ks * 32);
            acc0 = __builtin_amdgcn_mfma_f32_16x16x32_bf16(ahi, bhi, acc0, 0, 0, 0);
            acc0 = __builtin_amdgcn_mfma_f32_16x16x32_bf16(ahi, blo, acc0, 0, 0, 0);
            acc0 = __builtin_amdgcn_mfma_f32_16x16x32_bf16(alo, bhi, acc0, 0, 0, 0);

            ahi = *(const short8v*)(ar + 16 * AS + ks * 32);
            alo = *(const short8v*)(al + 16 * AS + ks * 32);
            acc1 = __builtin_amdgcn_mfma_f32_16x16x32_bf16(ahi, bhi, acc1, 0, 0, 0);
            acc1 = __builtin_amdgcn_mfma_f32_16x16x32_bf16(ahi, blo, acc1, 0, 0, 0);
            acc1 = __builtin_amdgcn_mfma_f32_16x16x32_bf16(alo, bhi, acc1, 0, 0, 0);
        }
    }
    __syncthreads();   // all A-tile reads complete; safe to overlay H

    float (*H)[HS] = (float (*)[HS])smem;
    if (w < 6) {
        #pragma unroll
        for (int r = 0; r < 4; ++r) {
            H[lq * 4 + r][w * 16 + lm]      = acc0[r];
            H[16 + lq * 4 + r][w * 16 + lm] = acc1[r];
        }
    }

    // ---- wait for scan results (device-scope acquire) ----
    if (tid == 0) {
        while (__hip_atomic_load((unsigned*)(ws + WS_FLAG),
                                 __ATOMIC_ACQUIRE, __HIP_MEMORY_SCOPE_AGENT) == 0u)
            __builtin_amdgcn_s_sleep(32);
    }
    __syncthreads();   // H ready (all waves) + flag observed

    // ================= in-block MFMA epilogue =================
    // wave w: token tile tt = w&3 (16 tokens), vocab tile n = w>>2 (16 rows)
    {
        const int tt = w & 3;
        const int n  = w >> 2;
        const int t  = tt * 16 + lm;

        short8v Ch0, Cl0, Ch1, Cl1, Ch2, Cl2, Uh, Ul, Vh, Vl;
        split_bf16(ws + WS_COEF + t * NBASIS + lq * 8,      Ch0, Cl0);
        split_bf16(ws + WS_COEF + t * NBASIS + 32 + lq * 8, Ch1, Cl1);
        split_bf16(ws + WS_COEF + t * NBASIS + 64 + lq * 8, Ch2, Cl2);
        split_bf16(ws + WS_U  + t * NB + lq * 8, Uh, Ul);
        split_bf16(ws + WS_VV + t * NB + lq * 8, Vh, Vl);

        float Cr[4];
        #pragma unroll
        for (int r = 0; r < 4; ++r) Cr[r] = ws[WS_C + tt * 16 + lq * 4 + r];

        const float* hrow = &H[n * 16 + lm][lq * 8];

        // kstep 0: G (split Hf) and G2 (split Hf^2)
        float4 fa = *(const float4*)hrow;
        float4 fb = *(const float4*)(hrow + 4);
        float f0[8] = {fa.x, fa.y, fa.z, fa.w, fb.x, fb.y, fb.z, fb.w};
        short8v Bh0, Bl0, Qh, Ql;
        split8r(f0, Bh0, Bl0);
        float g2[8];
        #pragma unroll
        for (int j = 0; j < 8; ++j) g2[j] = f0[j] * f0[j];
        split8r(g2, Qh, Ql);

        f32x4 ah = {0.f,0.f,0.f,0.f}, aa = {0.f,0.f,0.f,0.f}, ab = {0.f,0.f,0.f,0.f};

        ah = __builtin_amdgcn_mfma_f32_16x16x32_bf16(Ch0, Bh0, ah, 0, 0, 0);
        ah = __builtin_amdgcn_mfma_f32_16x16x32_bf16(Ch0, Bl0, ah, 0, 0, 0);
        ah = __builtin_amdgcn_mfma_f32_16x16x32_bf16(Cl0, Bh0, ah, 0, 0, 0);

        aa = __builtin_amdgcn_mfma_f32_16x16x32_bf16(Uh, Qh, aa, 0, 0, 0);
        aa = __builtin_amdgcn_mfma_f32_16x16x32_bf16(Uh, Ql, aa, 0, 0, 0);
        aa = __builtin_amdgcn_mfma_f32_16x16x32_bf16(Ul, Qh, aa, 0, 0, 0);

        ab = __builtin_amdgcn_mfma_f32_16x16x32_bf16(Vh, Bh0, ab, 0, 0, 0);
        ab = __builtin_amdgcn_mfma_f32_16x16x32_bf16(Vh, Bl0, ab, 0, 0, 0);
        ab = __builtin_amdgcn_mfma_f32_16x16x32_bf16(Vl, Bh0, ab, 0, 0, 0);

        // ksteps 1,2 of h (Hf cols 32..95 from LDS)
        short8v Bh, Bl;
        {
            float4 ga4 = *(const float4*)(hrow + 32);
            float4 gb4 = *(const float4*)(hrow + 36);
            float f1[8] = {ga4.x, ga4.y, ga4.z, ga4.w, gb4.x, gb4.y, gb4.z, gb4.w};
            split8r(f1, Bh, Bl);
        }
        ah = __builtin_amdgcn_mfma_f32_16x16x32_bf16(Ch1, Bh, ah, 0, 0, 0);
        ah = __builtin_amdgcn_mfma_f32_16x16x32_bf16(Ch1, Bl, ah, 0, 0, 0);
        ah = __builtin_amdgcn_mfma_f32_16x16x32_bf16(Cl1, Bh, ah, 0, 0, 0);

        {
            float4 ga4 = *(const float4*)(hrow + 64);
            float4 gb4 = *(const float4*)(hrow + 68);
            float f1[8] = {ga4.x, ga4.y, ga4.z, ga4.w, gb4.x, gb4.y, gb4.z, gb4.w};
            split8r(f1, Bh, Bl);
        }
        ah = __builtin_amdgcn_mfma_f32_16x16x32_bf16(Ch2, Bh, ah, 0, 0, 0);
        ah = __builtin_amdgcn_mfma_f32_16x16x32_bf16(Ch2, Bl, ah, 0, 0, 0);
        ah = __builtin_amdgcn_mfma_f32_16x16x32_bf16(Cl2, Bh, ah, 0, 0, 0);

        // combine + store: D row = token (lq*4+r), col = vocab (lm)
        #pragma unroll
        for (int r = 0; r < 4; ++r) {
            const float h = ah[r];
            out[(long)(tt * 16 + lq * 4 + r) * VOCAB + vb + n * 16 + lm] =
                fmaf(h, ab[r], fmaf(h * h, Cr[r], aa[r]));
        }
    }
}

// ===========================================================================
// Fallback path (verified round-11), used when ws is too small.
// ===========================================================================
__global__ __launch_bounds__(64) void foam_scan5(
    const float* __restrict__ p_mdb, const float* __restrict__ p_ns,
    float* __restrict__ ws)
{
    const int l = threadIdx.x;
    const int b = l & 31;

    __shared__ float S2[SEQ][NBASIS];

    const float* wsS = ws + WS_S;
    for (int e = l; e < SEQ * NBASIS / 4; e += 64)
        ((float4*)S2)[e] = ((const float4*)(wsS + NB * NBASIS))[e];

    float gbb_row[NB];
    {
        const float4* pa = (const float4*)(wsS + b * NBASIS);
        #pragma unroll
        for (int i = 0; i < 8; ++i) {
            float4 va = pa[i];
            gbb_row[4*i] = va.x; gbb_row[4*i+1] = va.y;
            gbb_row[4*i+2] = va.z; gbb_row[4*i+3] = va.w;
        }
    }
    const float diag = wsS[(NB + l) * NBASIS + NB + l];
    const float bn2  = wsS[b * NBASIS + b];

    const float LOG2E = 1.44269504088896f;
    const float mdb2  = p_mdb[0] * LOG2E;
    const float sens2 = fabsf(p_ns[0]) * LOG2E;
    const float sl2e  = 0.0625f * LOG2E;

    __syncthreads();

    float y = 0.f, mm2 = 0.f;
    float m1 = 0.f, m2 = 0.f;

    float* wsCOEF = ws + WS_COEF;
    float* wsUV   = ws + WS_U;
    float* wsC    = ws + WS_C;

    float gxcol = S2[0][b];
    float xcol1 = S2[0][l];
    float xcol2 = S2[0][32 + l];

    const int uvoff = (l >> 5) * (SEQ * NB);

    #pragma unroll 4
    for (int t = 0; t < SEQ; ++t) {
        const float xdm = sum64(fmaf(xcol2, m2, xcol1 * m1));
        const float px  = rdlane(diag, t);
        const float nov = (mm2 > 9.8e-17f)
                        ? (1.f - xdm * fast_rsq(px * mm2))
                        : 1.f;
        const float decay = fast_rcp(1.f + fast_exp2(fmaf(sens2, nov, -mdb2)));
        const float omd = 1.f - decay;

        wsCOEF[t * NBASIS + l] = fmaf(decay, m1, (l == NB + t) ? 1.f : 0.f);
        if (l >= 32)
            wsCOEF[t * NBASIS + 32 + l] = fmaf(decay, m2, (l == t) ? 1.f : 0.f);

        const float q = px + 2.f * decay * xdm + decay * decay * mm2;
        const float c = fmaf(decay, y, gxcol);

        const int tn = (t + 1) & (SEQ - 1);
        const float gxn = S2[tn][b];
        const float xn1 = S2[tn][l];
        const float xn2 = S2[tn][32 + l];

        const float cq2 = (c - q) * sl2e;
        float alpha = 1.f, p = 0.f;
        #pragma unroll
        for (int k = 0; k <= NEQ; ++k) {
            const float ev = fast_exp2(alpha * cq2);
            const float sm = sum32h(ev);
            const float r  = fast_rcp(sm);
            if (k < NEQ) {
                const float ae = alpha * ev;
                alpha = fmaf(-ae, r, alpha);
            } else {
                p = ev * r;
            }
        }

        const float oma = 1.f - alpha;
        const float s2v = alpha * alpha * bn2 + 2.f * alpha * oma * c + oma * oma * q;
        const float g = p * fast_rcp(s2v + 1e-20f);
        const float uu  = g * alpha * alpha;
        const float vv2 = 2.f * g * alpha * oma;
        wsUV[uvoff + t * NB + b] = (l < NB) ? uu : vv2;

        float asg[NB];
        #pragma unroll
        for (int j = 0; j < NB; ++j) asg[j] = rdlane(alpha, j);
        float ga0 = 0.f, ga1 = 0.f, ga2 = 0.f, ga3 = 0.f;
        #pragma unroll
        for (int j = 0; j < NB; j += 4) {
            ga0 = fmaf(gbb_row[j],     asg[j],     ga0);
            ga1 = fmaf(gbb_row[j + 1], asg[j + 1], ga1);
            ga2 = fmaf(gbb_row[j + 2], asg[j + 2], ga2);
            ga3 = fmaf(gbb_row[j + 3], asg[j + 3], ga3);
        }
        const float ga = (ga0 + ga1) + (ga2 + ga3);

        const float r0 = sum32h(alpha);
        const float r1 = sum32h(alpha * c);
        const float r2 = sum32h(alpha * y);
        const float r3 = sum32h(alpha * ga);
        const float Cp = sum32h(g * oma * oma);
        if (l == 0) wsC[t] = Cp;

        const float msc = (32.f - r0) * (1.f / 32.f);
        const float k1 = decay * fmaf(omd, msc, 1.f);
        const float mmxwm = fmaf(decay, mm2, xdm);
        const float mmms = fmaf(msc, mmxwm, r2 * (1.f / 32.f));
        const float u1sq = r3 * (1.f / 1024.f);
        const float msms = fmaf(msc * msc, q, fmaf(2.f * msc, r1 * (1.f / 32.f), u1sq));
        mm2 = decay * decay * mm2 + 2.f * decay * omd * mmms + omd * omd * msms;

        y = fmaf(k1, y, omd * fmaf(msc, gxcol, ga * (1.f / 32.f)));

        const float inc1 = (l < NB) ? omd * alpha * (1.f / 32.f)
                                    : ((l == NB + t) ? omd * msc : 0.f);
        m1 = fmaf(k1, m1, inc1);
        m2 = fmaf(k1, m2, (t >= NB && l == t) ? omd * msc : 0.f);

        gxcol = gxn;
        xcol1 = xn1;
        xcol2 = xn2;
    }
}

__global__ __launch_bounds__(256) void foam_recon(
    const int* __restrict__ tokens, const float* __restrict__ E,
    const float* __restrict__ bubbles, float* __restrict__ ws)
{
    const int i = blockIdx.x;
    const int d = threadIdx.x;
    __shared__ float cfs[NBASIS];
    __shared__ int stok[SEQ];

    float val;
    if (i < NB) {
        val = bubbles[i * D + d];
    } else {
        const int t = i - NB;
        if (d < NBASIS) cfs[d] = ws[WS_COEF + t * NBASIS + d];
        if (d < SEQ) stok[d] = tokens[d];
        __syncthreads();
        float acc = 0.f;
        #pragma unroll 8
        for (int bb = 0; bb < NB; ++bb) acc = fmaf(cfs[bb], bubbles[bb * D + d], acc);
        #pragma unroll 8
        for (int j = 0; j < SEQ; ++j) acc = fmaf(cfs[32 + j], E[(long)stok[j] * D + d], acc);
        val = acc;
    }
    short hi, lo;
    split1(val, hi, lo);
    unsigned short* Whl = (unsigned short*)(ws + WS_WHL);
    Whl[i * D + d]               = (unsigned short)hi;
    Whl[NBASIS * D + i * D + d]  = (unsigned short)lo;
}

#define US 36

__global__ __launch_bounds__(512, 2) void foam_mfma_logits(
    const float* __restrict__ E,
    const float* __restrict__ ws,
    float* __restrict__ out)
{
    __shared__ short Ah[MROWS * AS];
    __shared__ short Al[MROWS * AS];
    __shared__ float H[MROWS][HS];
    __shared__ float us[SEQ * US];
    __shared__ float vs[SEQ * US];
    __shared__ float Cs[SEQ];

    const int tid = threadIdx.x;
    const int w = tid >> 6;
    const int l = tid & 63;
    const int lm = l & 15;
    const int lq = l >> 4;

    const long vb = (long)blockIdx.x * MROWS;

    {
        const float* src = E + vb * D;
        const int base = tid * 16;
        const int row = base >> 8;
        const int col = base & 255;
        float4 v0 = *(const float4*)(src + base);
        float4 v1 = *(const float4*)(src + base + 4);
        float4 v2 = *(const float4*)(src + base + 8);
        float4 v3 = *(const float4*)(src + base + 12);
        float f[16] = {v0.x,v0.y,v0.z,v0.w, v1.x,v1.y,v1.z,v1.w,
                       v2.x,v2.y,v2.z,v2.w, v3.x,v3.y,v3.z,v3.w};
        short8v h0, h1, l0, l1;
        #pragma unroll
        for (int j = 0; j < 8; ++j) { short hi, lo; split1(f[j], hi, lo); h0[j] = hi; l0[j] = lo; }
        #pragma unroll
        for (int j = 0; j < 8; ++j) { short hi, lo; split1(f[8+j], hi, lo); h1[j] = hi; l1[j] = lo; }
        *(short8v*)&Ah[row * AS + col]     = h0;
        *(short8v*)&Ah[row * AS + col + 8] = h1;
        *(short8v*)&Al[row * AS + col]     = l0;
        *(short8v*)&Al[row * AS + col + 8] = l1;
    }

    for (int i = tid; i < SEQ * NB; i += 512) {
        int t = i >> 5, bb = i & 31;
        us[t * US + bb] = ws[WS_U + i];
        vs[t * US + bb] = ws[WS_VV + i];
    }
    if (tid < SEQ) Cs[tid] = ws[WS_C + tid];
    __syncthreads();

    if (w < 6) {
        const int n = w * 16 + lm;
        const short* bh = (const short*)(ws + WS_WHL) + n * D + lq * 8;
        const short* bl = bh + NBASIS * D;
        const short* ar = &Ah[lm * AS + lq * 8];
        const short* al = &Al[lm * AS + lq * 8];

        f32x4 acc0 = {0.f,0.f,0.f,0.f}, acc1 = {0.f,0.f,0.f,0.f};

        #pragma unroll
        for (int ks = 0; ks < 8; ++ks) {
            const short8v bhi = *(const short8v*)(bh + ks * 32);
            const short8v blo = *(const short8v*)(bl + ks * 32);

            short8v ahi = *(const short8v*)(ar + ks * 32);
            short8v alo = *(const short8v*)(al + ks * 32);
            acc0 = __builtin_amdgcn_mfma_f32_16x16x32_bf16(ahi, bhi, acc0, 0, 0, 0);
            acc0 = __builtin_amdgcn_mfma_f32_16x16x32_bf16(ahi, blo, acc0, 0, 0, 0);
            acc0 = __builtin_amdgcn_mfma_f32_16x16x32_bf16(alo, bhi, acc0, 0, 0, 0);

            ahi = *(const short8v*)(ar + 16 * AS + ks * 32);
            alo = *(const short8v*)(al + 16 * AS + ks * 32);
            acc1 = __builtin_amdgcn_mfma_f32_16x16x32_bf16(ahi, bhi, acc1, 0, 0, 0);
            acc1 = __builtin_amdgcn_mfma_f32_16x16x32_bf16(ahi, blo, acc1, 0, 0, 0);
            acc1 = __builtin_amdgcn_mfma_f32_16x16x32_bf16(alo, bhi, acc1, 0, 0, 0);
        }
        #pragma unroll
        for (int r = 0; r < 4; ++r) {
            H[lq * 4 + r][w * 16 + lm]      = acc0[r];
            H[16 + lq * 4 + r][w * 16 + lm] = acc1[r];
        }
    }
    __syncthreads();

    const int t0 = w * 8 + lq;
    const int t1 = t0 + 4;
    const float c0 = Cs[t0], c1 = Cs[t1];

    #pragma unroll
    for (int mt = 0; mt < 2; ++mt) {
        const int row = mt * 16 + lm;
        float G[NB];
        #pragma unroll
        for (int i = 0; i < 8; ++i)
            *(float4*)&G[4 * i] = *(const float4*)&H[row][4 * i];

        float a0 = 0.f, b0 = 0.f, a1 = 0.f, b1 = 0.f;
        #pragma unroll
        for (int i = 0; i < 8; ++i) {
            float g0 = G[4*i], g1 = G[4*i+1], g2c = G[4*i+2], g3 = G[4*i+3];
            float q0 = g0*g0, q1 = g1*g1, q2 = g2c*g2c, q3 = g3*g3;
            float4 u0 = *(const float4*)&us[t0 * US + 4 * i];
            float4 v0 = *(const float4*)&vs[t0 * US + 4 * i];
            float4 u1 = *(const float4*)&us[t1 * US + 4 * i];
            float4 v1 = *(const float4*)&vs[t1 * US + 4 * i];
            a0 = fmaf(u0.x, q0, fmaf(u0.y, q1, fmaf(u0.z, q2, fmaf(u0.w, q3, a0))));
            b0 = fmaf(v0.x, g0, fmaf(v0.y, g1, fmaf(v0.z, g2c, fmaf(v0.w, g3, b0))));
            a1 = fmaf(u1.x, q0, fmaf(u1.y, q1, fmaf(u1.z, q2, fmaf(u1.w, q3, a1))));
            b1 = fmaf(v1.x, g0, fmaf(v1.y, g1, fmaf(v1.z, g2c, fmaf(v1.w, g3, b1))));
        }
        const float h0 = H[row][32 + t0];
        const float h1 = H[row][32 + t1];
        out[(long)t0 * VOCAB + vb + row] = fmaf(h0, b0, fmaf(h0 * h0, c0, a0));
        out[(long)t1 * VOCAB + vb + row] = fmaf(h1, b1, fmaf(h1 * h1, c1, a1));
    }
}

extern "C" void kernel_launch(void* const* d_in, const int* in_sizes, int n_in,
                              void* d_out, int out_size, void* d_ws, size_t ws_size,
                              hipStream_t stream) {
    const int*   tokens  = (const int*)d_in[0];
    const float* E       = (const float*)d_in[1];
    const float* bubbles = (const float*)d_in[2];
    const float* mdb     = (const float*)d_in[3];
    const float* ns      = (const float*)d_in[4];
    float* out = (float*)d_out;
    float* ws  = (float*)d_ws;

    const size_t need = ((size_t)WS_FLAG + 1) * sizeof(float);

    hipLaunchKernelGGL(foam_prep, dim3(NBASIS), dim3(256), 0, stream,
                       tokens, E, bubbles, ws);

    if (ws_size >= need) {
        // fast path: single fused kernel (scan ∥ GEMM, flag-synced epilogue)
        hipLaunchKernelGGL(foam_fused, dim3(VOCAB / MROWS + 1), dim3(512), 0, stream,
                           E, mdb, ns, ws, out);
    } else {
        // fallback: verified round-11 pipeline
        hipLaunchKernelGGL(foam_scan5, dim3(1), dim3(64), 0, stream, mdb, ns, ws);
        hipLaunchKernelGGL(foam_recon, dim3(NBASIS), dim3(256), 0, stream,
                           tokens, E, bubbles, ws);
        hipLaunchKernelGGL(foam_mfma_logits, dim3(VOCAB / MROWS), dim3(512), 0, stream,
                           E, ws, out);
    }
}

// Round 17
// 91.649 us; speedup vs baseline: 21.7161x; 21.7161x over previous
//
#include <hip/hip_runtime.h>
#include <math.h>

#define VOCAB 32000
#define D 256
#define NB 32
#define NEQ 5
#define SEQ 64
#define NBASIS 96   // 32 bubbles + 64 token vectors

// ws layout (float offsets)
#define WS_S     0                          // [96][96] Gram of basis U=[B;X]
#define WS_COEF  (NBASIS*NBASIS)            // [SEQ][96] x_wm coefficients
#define WS_U     (WS_COEF + SEQ*NBASIS)     // [SEQ][NB]
#define WS_VV    (WS_U + SEQ*NB)            // [SEQ][NB]  (must stay right after WS_U)
#define WS_C     (WS_VV + SEQ*NB)           // [SEQ]
#define WS_WHL   (WS_C + SEQ)               // ushort[2][96][256]: basis hi plane, lo plane
#define WS_HF    (WS_WHL + NBASIS*D/2*2)    // [VOCAB][96] fp32 Hf = E @ U^T (fast path)

typedef __attribute__((ext_vector_type(8))) short short8v;
typedef __attribute__((ext_vector_type(4))) float f32x4;

// ---------------------------------------------------------------------------
// Fast cross-lane / math primitives
// ---------------------------------------------------------------------------
template <int CTRL>
__device__ __forceinline__ float dpp_add(float x) {
    int yi = __builtin_amdgcn_update_dpp(0, __float_as_int(x), CTRL, 0xF, 0xF, true);
    return x + __int_as_float(yi);
}
__device__ __forceinline__ float xor16_add(float x) {
    float a, b;
    asm("v_mov_b32 %0, %2\n\t"
        "v_mov_b32 %1, %2\n\t"
        "v_permlane16_swap_b32 %0, %1"
        : "=&v"(a), "=&v"(b) : "v"(x));
    return a + b;
}
__device__ __forceinline__ float xor32_add(float x) {
    float a, b;
    asm("v_mov_b32 %0, %2\n\t"
        "v_mov_b32 %1, %2\n\t"
        "v_permlane32_swap_b32 %0, %1"
        : "=&v"(a), "=&v"(b) : "v"(x));
    return a + b;
}
__device__ __forceinline__ float sum32h(float x) {
    x = dpp_add<0xB1>(x);    // xor 1
    x = dpp_add<0x4E>(x);    // xor 2
    x = dpp_add<0x124>(x);   // row_ror:4
    x = dpp_add<0x128>(x);   // row_ror:8
    return xor16_add(x);
}
__device__ __forceinline__ float sum64(float x) {
    return xor32_add(sum32h(x));
}
__device__ __forceinline__ float rdlane(float v, int lane) {
    return __int_as_float(__builtin_amdgcn_readlane(__float_as_int(v), lane));
}
__device__ __forceinline__ float fast_rcp(float x) {
    float r; asm("v_rcp_f32 %0, %1" : "=v"(r) : "v"(x)); return r;
}
__device__ __forceinline__ float fast_sqrt(float x) {
    float r; asm("v_sqrt_f32 %0, %1" : "=v"(r) : "v"(x)); return r;
}
__device__ __forceinline__ float fast_exp2(float x) {
    float r; asm("v_exp_f32 %0, %1" : "=v"(r) : "v"(x)); return r;
}
__device__ __forceinline__ void split1(float x, short& hi, short& lo) {
    unsigned xb = __builtin_bit_cast(unsigned, x);
    unsigned hb = xb & 0xFFFF0000u;
    float fl = x - __builtin_bit_cast(float, hb);
    hi = (short)(hb >> 16);
    lo = (short)(__builtin_bit_cast(unsigned, fl) >> 16);
}
// split 8 f32 (from memory) -> bf16 hi/lo fragments
__device__ __forceinline__ void split_bf16(const float* p, short8v& hi, short8v& lo) {
    float4 f0 = *(const float4*)p;
    float4 f1 = *(const float4*)(p + 4);
    float f[8] = {f0.x, f0.y, f0.z, f0.w, f1.x, f1.y, f1.z, f1.w};
    #pragma unroll
    for (int j = 0; j < 8; ++j) { short h, l; split1(f[j], h, l); hi[j] = h; lo[j] = l; }
}
// split 8 f32 (register array) -> bf16 hi/lo fragments
__device__ __forceinline__ void split8r(const float* f, short8v& hi, short8v& lo) {
    #pragma unroll
    for (int j = 0; j < 8; ++j) { short h, l; split1(f[j], h, l); hi[j] = h; lo[j] = l; }
}

// ---------------------------------------------------------------------------
// K1: Gram matrix + U bf16 hi/lo planes (U = [bubbles; E[tokens]]).
// ---------------------------------------------------------------------------
__global__ __launch_bounds__(256) void foam_prep(
    const int* __restrict__ tokens, const float* __restrict__ E,
    const float* __restrict__ bubbles, float* __restrict__ ws)
{
    const int bid = blockIdx.x;    // basis row 0..95
    const int d = threadIdx.x;

    {
        const float val = (bid < NB) ? bubbles[bid * D + d]
                                     : E[(long)tokens[bid - NB] * D + d];
        short hi, lo;
        split1(val, hi, lo);
        unsigned short* Uhl = (unsigned short*)(ws + WS_WHL);
        Uhl[bid * D + d]              = (unsigned short)hi;
        Uhl[NBASIS * D + bid * D + d] = (unsigned short)lo;
    }

    const int idx = bid * 256 + d;
    if (idx < NBASIS * NBASIS) {
        const int i = idx / NBASIS, j = idx % NBASIS;
        const float4* ra = (const float4*)((i < NB) ? (bubbles + i * D)
                                                    : (E + (long)tokens[i - NB] * D));
        const float4* rb = (const float4*)((j < NB) ? (bubbles + j * D)
                                                    : (E + (long)tokens[j - NB] * D));
        float a0 = 0.f, a1 = 0.f, a2 = 0.f, a3 = 0.f;
        #pragma unroll
        for (int k = 0; k < D / 4; k += 4) {
            float4 x, y;
            x = ra[k];     y = rb[k];
            a0 = fmaf(x.x, y.x, fmaf(x.y, y.y, fmaf(x.z, y.z, fmaf(x.w, y.w, a0))));
            x = ra[k + 1]; y = rb[k + 1];
            a1 = fmaf(x.x, y.x, fmaf(x.y, y.y, fmaf(x.z, y.z, fmaf(x.w, y.w, a1))));
            x = ra[k + 2]; y = rb[k + 2];
            a2 = fmaf(x.x, y.x, fmaf(x.y, y.y, fmaf(x.z, y.z, fmaf(x.w, y.w, a2))));
            x = ra[k + 3]; y = rb[k + 3];
            a3 = fmaf(x.x, y.x, fmaf(x.y, y.y, fmaf(x.z, y.z, fmaf(x.w, y.w, a3))));
        }
        ws[WS_S + i * NBASIS + j] = (a0 + a1) + (a2 + a3);
    }
}

// ---------------------------------------------------------------------------
// KF: fused kernel. Block 0 = serial scan; blocks 1..1000 = GEMM Hf = E @ U^T.
// ---------------------------------------------------------------------------
#define MROWS 32
#define AS 264    // LDS A row stride in bf16 elems

__global__ __launch_bounds__(512) void foam_fused(
    const float* __restrict__ E,
    const float* __restrict__ p_mdb, const float* __restrict__ p_ns,
    float* __restrict__ ws)
{
    __shared__ __align__(16) char smem[MROWS * AS * 2 * 2];   // 33792 B
    const int tid = threadIdx.x;

    if (blockIdx.x == 0) {
        // ================= scan (verified round-9/11 body) =================
        float (*S2)[NBASIS] = (float (*)[NBASIS])smem;
        const int l = tid;
        const int b = l & 31;
        const float* wsS = ws + WS_S;

        for (int e = l; e < SEQ * NBASIS / 4; e += 64)
            ((float4*)S2)[e] = ((const float4*)(wsS + NB * NBASIS))[e];

        float gbb_row[NB];
        {
            const float4* pa = (const float4*)(wsS + b * NBASIS);
            #pragma unroll
            for (int i = 0; i < 8; ++i) {
                float4 va = pa[i];
                gbb_row[4*i] = va.x; gbb_row[4*i+1] = va.y;
                gbb_row[4*i+2] = va.z; gbb_row[4*i+3] = va.w;
            }
        }
        const float diag = wsS[(NB + (l & 63)) * NBASIS + NB + (l & 63)];
        const float bn2  = wsS[b * NBASIS + b];

        const float LOG2E = 1.44269504088896f;
        const float mdb2  = p_mdb[0] * LOG2E;
        const float sens2 = fabsf(p_ns[0]) * LOG2E;
        const float sl2e  = 0.0625f * LOG2E;

        __syncthreads();
        if (l >= 64) return;

        float y = 0.f, mm2 = 0.f;
        float m1 = 0.f, m2 = 0.f;

        float* wsCOEF = ws + WS_COEF;
        float* wsUV   = ws + WS_U;
        float* wsC    = ws + WS_C;

        float gxcol = S2[0][b];
        float xcol1 = S2[0][l];
        float xcol2 = S2[0][32 + l];

        const int uvoff = (l >> 5) * (SEQ * NB);

        #pragma unroll 4
        for (int t = 0; t < SEQ; ++t) {
            const float xdm = sum64(fmaf(xcol2, m2, xcol1 * m1));
            const float px  = rdlane(diag, t);
            const float nov = (mm2 > 9.8e-17f)
                            ? (1.f - xdm * fast_rcp(fast_sqrt(px * mm2)))
                            : 1.f;
            const float decay = fast_rcp(1.f + fast_exp2(fmaf(sens2, nov, -mdb2)));
            const float omd = 1.f - decay;

            wsCOEF[t * NBASIS + l] = fmaf(decay, m1, (l == NB + t) ? 1.f : 0.f);
            if (l >= 32)
                wsCOEF[t * NBASIS + 32 + l] = fmaf(decay, m2, (l == t) ? 1.f : 0.f);

            const float q = px + 2.f * decay * xdm + decay * decay * mm2;
            const float c = fmaf(decay, y, gxcol);

            const int tn = (t + 1) & (SEQ - 1);
            const float gxn = S2[tn][b];
            const float xn1 = S2[tn][l];
            const float xn2 = S2[tn][32 + l];

            const float cq2 = (c - q) * sl2e;
            float alpha = 1.f, p = 0.f;
            #pragma unroll
            for (int k = 0; k <= NEQ; ++k) {
                const float ev = fast_exp2(alpha * cq2);
                const float sm = sum32h(ev);
                const float r  = fast_rcp(sm);
                if (k < NEQ) {
                    const float ae = alpha * ev;
                    alpha = fmaf(-ae, r, alpha);
                } else {
                    p = ev * r;
                }
            }

            const float oma = 1.f - alpha;
            const float s2v = alpha * alpha * bn2 + 2.f * alpha * oma * c + oma * oma * q;
            const float g = p * fast_rcp(s2v + 1e-20f);
            const float uu  = g * alpha * alpha;
            const float vv2 = 2.f * g * alpha * oma;
            wsUV[uvoff + t * NB + b] = (l < NB) ? uu : vv2;

            float asg[NB];
            #pragma unroll
            for (int j = 0; j < NB; ++j) asg[j] = rdlane(alpha, j);
            float ga0 = 0.f, ga1 = 0.f, ga2 = 0.f, ga3 = 0.f;
            #pragma unroll
            for (int j = 0; j < NB; j += 4) {
                ga0 = fmaf(gbb_row[j],     asg[j],     ga0);
                ga1 = fmaf(gbb_row[j + 1], asg[j + 1], ga1);
                ga2 = fmaf(gbb_row[j + 2], asg[j + 2], ga2);
                ga3 = fmaf(gbb_row[j + 3], asg[j + 3], ga3);
            }
            const float ga = (ga0 + ga1) + (ga2 + ga3);

            const float r0 = sum32h(alpha);
            const float r1 = sum32h(alpha * c);
            const float r2 = sum32h(alpha * y);
            const float r3 = sum32h(alpha * ga);
            const float Cp = sum32h(g * oma * oma);
            if (l == 0) wsC[t] = Cp;

            const float msc = (32.f - r0) * (1.f / 32.f);
            const float k1 = decay * fmaf(omd, msc, 1.f);
            const float mmxwm = fmaf(decay, mm2, xdm);
            const float mmms = fmaf(msc, mmxwm, r2 * (1.f / 32.f));
            const float u1sq = r3 * (1.f / 1024.f);
            const float msms = fmaf(msc * msc, q, fmaf(2.f * msc, r1 * (1.f / 32.f), u1sq));
            mm2 = decay * decay * mm2 + 2.f * decay * omd * mmms + omd * omd * msms;

            y = fmaf(k1, y, omd * fmaf(msc, gxcol, ga * (1.f / 32.f)));

            const float inc1 = (l < NB) ? omd * alpha * (1.f / 32.f)
                                        : ((l == NB + t) ? omd * msc : 0.f);
            m1 = fmaf(k1, m1, inc1);
            m2 = fmaf(k1, m2, (t >= NB && l == t) ? omd * msc : 0.f);

            gxcol = gxn;
            xcol1 = xn1;
            xcol2 = xn2;
        }
        return;
    }

    // ================= GEMM blocks: Hf = E @ U^T =================
    short* Ah = (short*)smem;
    short* Al = Ah + MROWS * AS;

    const int w = tid >> 6;
    const int l = tid & 63;
    const int lm = l & 15;
    const int lq = l >> 4;

    const long vb = (long)(blockIdx.x - 1) * MROWS;

    {
        const float* src = E + vb * D;
        const int base = tid * 16;
        const int row = base >> 8;
        const int col = base & 255;
        float4 v0 = *(const float4*)(src + base);
        float4 v1 = *(const float4*)(src + base + 4);
        float4 v2 = *(const float4*)(src + base + 8);
        float4 v3 = *(const float4*)(src + base + 12);
        float f[16] = {v0.x,v0.y,v0.z,v0.w, v1.x,v1.y,v1.z,v1.w,
                       v2.x,v2.y,v2.z,v2.w, v3.x,v3.y,v3.z,v3.w};
        short8v h0, h1, l0, l1;
        #pragma unroll
        for (int j = 0; j < 8; ++j) { short hi, lo; split1(f[j], hi, lo); h0[j] = hi; l0[j] = lo; }
        #pragma unroll
        for (int j = 0; j < 8; ++j) { short hi, lo; split1(f[8+j], hi, lo); h1[j] = hi; l1[j] = lo; }
        *(short8v*)&Ah[row * AS + col]     = h0;
        *(short8v*)&Ah[row * AS + col + 8] = h1;
        *(short8v*)&Al[row * AS + col]     = l0;
        *(short8v*)&Al[row * AS + col + 8] = l1;
    }
    __syncthreads();

    if (w >= 6) return;

    const int n = w * 16 + lm;
    const short* bh = (const short*)(ws + WS_WHL) + n * D + lq * 8;
    const short* bl = bh + NBASIS * D;
    const short* ar = &Ah[lm * AS + lq * 8];
    const short* al = &Al[lm * AS + lq * 8];

    f32x4 acc0 = {0.f,0.f,0.f,0.f}, acc1 = {0.f,0.f,0.f,0.f};

    #pragma unroll
    for (int ks = 0; ks < 8; ++ks) {
        const short8v bhi = *(const short8v*)(bh + ks * 32);
        const short8v blo = *(const short8v*)(bl + ks * 32);

        short8v ahi = *(const short8v*)(ar + ks * 32);
        short8v alo = *(const short8v*)(al + ks * 32);
        acc0 = __builtin_amdgcn_mfma_f32_16x16x32_bf16(ahi, bhi, acc0, 0, 0, 0);
        acc0 = __builtin_amdgcn_mfma_f32_16x16x32_bf16(ahi, blo, acc0, 0, 0, 0);
        acc0 = __builtin_amdgcn_mfma_f32_16x16x32_bf16(alo, bhi, acc0, 0, 0, 0);

        ahi = *(const short8v*)(ar + 16 * AS + ks * 32);
        alo = *(const short8v*)(al + 16 * AS + ks * 32);
        acc1 = __builtin_amdgcn_mfma_f32_16x16x32_bf16(ahi, bhi, acc1, 0, 0, 0);
        acc1 = __builtin_amdgcn_mfma_f32_16x16x32_bf16(ahi, blo, acc1, 0, 0, 0);
        acc1 = __builtin_amdgcn_mfma_f32_16x16x32_bf16(alo, bhi, acc1, 0, 0, 0);
    }

    float* Hf = ws + WS_HF;
    #pragma unroll
    for (int r = 0; r < 4; ++r) {
        Hf[(vb + lq * 4 + r) * NBASIS + w * 16 + lm]      = acc0[r];
        Hf[(vb + 16 + lq * 4 + r) * NBASIS + w * 16 + lm] = acc1[r];
    }
}

// ---------------------------------------------------------------------------
// KE: MFMA epilogue. Three small GEMMs + combine, zero LDS.
//   h = Hf @ coef^T, a = G2 @ us^T, b = G @ vs^T;  out = a + h*b + h^2*C[t].
// A-operand = token side (coef/us/vs, split-bf16, loaded once per wave);
// B-operand = Hf rows (f32 -> split in-register; kstep-0 reused for G/G2).
// Block: 256 thr = 4 waves (wave w owns tokens w*16..w*16+15); 4 v-tiles of 16.
// ---------------------------------------------------------------------------
__global__ __launch_bounds__(256) void foam_epilogue_mfma(
    const float* __restrict__ ws, float* __restrict__ out)
{
    const int tid = threadIdx.x;
    const int w = tid >> 6;        // wave -> token tile
    const int l = tid & 63;
    const int lm = l & 15;
    const int lq = l >> 4;

    const int t = w * 16 + lm;     // A-operand row (token)

    // A fragments (persistent): coef 3 ksteps, us/vs 1 kstep
    short8v Ch0, Cl0, Ch1, Cl1, Ch2, Cl2, Uh, Ul, Vh, Vl;
    split_bf16(ws + WS_COEF + t * NBASIS + lq * 8,      Ch0, Cl0);
    split_bf16(ws + WS_COEF + t * NBASIS + 32 + lq * 8, Ch1, Cl1);
    split_bf16(ws + WS_COEF + t * NBASIS + 64 + lq * 8, Ch2, Cl2);
    split_bf16(ws + WS_U  + t * NB + lq * 8, Uh, Ul);
    split_bf16(ws + WS_VV + t * NB + lq * 8, Vh, Vl);

    float Cr[4];
    #pragma unroll
    for (int r = 0; r < 4; ++r) Cr[r] = ws[WS_C + w * 16 + lq * 4 + r];

    const long VB = (long)blockIdx.x * 64;

    #pragma unroll
    for (int n = 0; n < 4; ++n) {
        const long v = VB + n * 16 + lm;              // B-operand col (vocab)
        const float* hrow = ws + WS_HF + v * NBASIS + lq * 8;

        // kstep 0: keep G (split Hf) and G2 (split Hf^2)
        float4 fa = *(const float4*)hrow;
        float4 fb = *(const float4*)(hrow + 4);
        float f0[8] = {fa.x, fa.y, fa.z, fa.w, fb.x, fb.y, fb.z, fb.w};
        short8v Bh0, Bl0, Qh, Ql;
        split8r(f0, Bh0, Bl0);
        float g2[8];
        #pragma unroll
        for (int j = 0; j < 8; ++j) g2[j] = f0[j] * f0[j];
        split8r(g2, Qh, Ql);

        f32x4 ah = {0.f,0.f,0.f,0.f}, aa = {0.f,0.f,0.f,0.f}, ab = {0.f,0.f,0.f,0.f};

        ah = __builtin_amdgcn_mfma_f32_16x16x32_bf16(Ch0, Bh0, ah, 0, 0, 0);
        ah = __builtin_amdgcn_mfma_f32_16x16x32_bf16(Ch0, Bl0, ah, 0, 0, 0);
        ah = __builtin_amdgcn_mfma_f32_16x16x32_bf16(Cl0, Bh0, ah, 0, 0, 0);

        aa = __builtin_amdgcn_mfma_f32_16x16x32_bf16(Uh, Qh, aa, 0, 0, 0);
        aa = __builtin_amdgcn_mfma_f32_16x16x32_bf16(Uh, Ql, aa, 0, 0, 0);
        aa = __builtin_amdgcn_mfma_f32_16x16x32_bf16(Ul, Qh, aa, 0, 0, 0);

        ab = __builtin_amdgcn_mfma_f32_16x16x32_bf16(Vh, Bh0, ab, 0, 0, 0);
        ab = __builtin_amdgcn_mfma_f32_16x16x32_bf16(Vh, Bl0, ab, 0, 0, 0);
        ab = __builtin_amdgcn_mfma_f32_16x16x32_bf16(Vl, Bh0, ab, 0, 0, 0);

        // ksteps 1,2 of h
        short8v Bh, Bl;
        split_bf16(hrow + 32, Bh, Bl);
        ah = __builtin_amdgcn_mfma_f32_16x16x32_bf16(Ch1, Bh, ah, 0, 0, 0);
        ah = __builtin_amdgcn_mfma_f32_16x16x32_bf16(Ch1, Bl, ah, 0, 0, 0);
        ah = __builtin_amdgcn_mfma_f32_16x16x32_bf16(Cl1, Bh, ah, 0, 0, 0);

        split_bf16(hrow + 64, Bh, Bl);
        ah = __builtin_amdgcn_mfma_f32_16x16x32_bf16(Ch2, Bh, ah, 0, 0, 0);
        ah = __builtin_amdgcn_mfma_f32_16x16x32_bf16(Ch2, Bl, ah, 0, 0, 0);
        ah = __builtin_amdgcn_mfma_f32_16x16x32_bf16(Cl2, Bh, ah, 0, 0, 0);

        // combine + store: D row = token (lq*4+r), col = vocab (lm)
        #pragma unroll
        for (int r = 0; r < 4; ++r) {
            const float h = ah[r];
            out[(long)(w * 16 + lq * 4 + r) * VOCAB + VB + n * 16 + lm] =
                fmaf(h, ab[r], fmaf(h * h, Cr[r], aa[r]));
        }
    }
}

// ===========================================================================
// Fallback path (verified round-11), used when ws is too small for Hf.
// ===========================================================================
__global__ __launch_bounds__(64) void foam_scan5(
    const float* __restrict__ p_mdb, const float* __restrict__ p_ns,
    float* __restrict__ ws)
{
    const int l = threadIdx.x;
    const int b = l & 31;

    __shared__ float S2[SEQ][NBASIS];

    const float* wsS = ws + WS_S;
    for (int e = l; e < SEQ * NBASIS / 4; e += 64)
        ((float4*)S2)[e] = ((const float4*)(wsS + NB * NBASIS))[e];

    float gbb_row[NB];
    {
        const float4* pa = (const float4*)(wsS + b * NBASIS);
        #pragma unroll
        for (int i = 0; i < 8; ++i) {
            float4 va = pa[i];
            gbb_row[4*i] = va.x; gbb_row[4*i+1] = va.y;
            gbb_row[4*i+2] = va.z; gbb_row[4*i+3] = va.w;
        }
    }
    const float diag = wsS[(NB + l) * NBASIS + NB + l];
    const float bn2  = wsS[b * NBASIS + b];

    const float LOG2E = 1.44269504088896f;
    const float mdb2  = p_mdb[0] * LOG2E;
    const float sens2 = fabsf(p_ns[0]) * LOG2E;
    const float sl2e  = 0.0625f * LOG2E;

    __syncthreads();

    float y = 0.f, mm2 = 0.f;
    float m1 = 0.f, m2 = 0.f;

    float* wsCOEF = ws + WS_COEF;
    float* wsUV   = ws + WS_U;
    float* wsC    = ws + WS_C;

    float gxcol = S2[0][b];
    float xcol1 = S2[0][l];
    float xcol2 = S2[0][32 + l];

    const int uvoff = (l >> 5) * (SEQ * NB);

    #pragma unroll 4
    for (int t = 0; t < SEQ; ++t) {
        const float xdm = sum64(fmaf(xcol2, m2, xcol1 * m1));
        const float px  = rdlane(diag, t);
        const float nov = (mm2 > 9.8e-17f)
                        ? (1.f - xdm * fast_rcp(fast_sqrt(px * mm2)))
                        : 1.f;
        const float decay = fast_rcp(1.f + fast_exp2(fmaf(sens2, nov, -mdb2)));
        const float omd = 1.f - decay;

        wsCOEF[t * NBASIS + l] = fmaf(decay, m1, (l == NB + t) ? 1.f : 0.f);
        if (l >= 32)
            wsCOEF[t * NBASIS + 32 + l] = fmaf(decay, m2, (l == t) ? 1.f : 0.f);

        const float q = px + 2.f * decay * xdm + decay * decay * mm2;
        const float c = fmaf(decay, y, gxcol);

        const int tn = (t + 1) & (SEQ - 1);
        const float gxn = S2[tn][b];
        const float xn1 = S2[tn][l];
        const float xn2 = S2[tn][32 + l];

        const float cq2 = (c - q) * sl2e;
        float alpha = 1.f, p = 0.f;
        #pragma unroll
        for (int k = 0; k <= NEQ; ++k) {
            const float ev = fast_exp2(alpha * cq2);
            const float sm = sum32h(ev);
            const float r  = fast_rcp(sm);
            if (k < NEQ) {
                const float ae = alpha * ev;
                alpha = fmaf(-ae, r, alpha);
            } else {
                p = ev * r;
            }
        }

        const float oma = 1.f - alpha;
        const float s2v = alpha * alpha * bn2 + 2.f * alpha * oma * c + oma * oma * q;
        const float g = p * fast_rcp(s2v + 1e-20f);
        const float uu  = g * alpha * alpha;
        const float vv2 = 2.f * g * alpha * oma;
        wsUV[uvoff + t * NB + b] = (l < NB) ? uu : vv2;

        float asg[NB];
        #pragma unroll
        for (int j = 0; j < NB; ++j) asg[j] = rdlane(alpha, j);
        float ga0 = 0.f, ga1 = 0.f, ga2 = 0.f, ga3 = 0.f;
        #pragma unroll
        for (int j = 0; j < NB; j += 4) {
            ga0 = fmaf(gbb_row[j],     asg[j],     ga0);
            ga1 = fmaf(gbb_row[j + 1], asg[j + 1], ga1);
            ga2 = fmaf(gbb_row[j + 2], asg[j + 2], ga2);
            ga3 = fmaf(gbb_row[j + 3], asg[j + 3], ga3);
        }
        const float ga = (ga0 + ga1) + (ga2 + ga3);

        const float r0 = sum32h(alpha);
        const float r1 = sum32h(alpha * c);
        const float r2 = sum32h(alpha * y);
        const float r3 = sum32h(alpha * ga);
        const float Cp = sum32h(g * oma * oma);
        if (l == 0) wsC[t] = Cp;

        const float msc = (32.f - r0) * (1.f / 32.f);
        const float k1 = decay * fmaf(omd, msc, 1.f);
        const float mmxwm = fmaf(decay, mm2, xdm);
        const float mmms = fmaf(msc, mmxwm, r2 * (1.f / 32.f));
        const float u1sq = r3 * (1.f / 1024.f);
        const float msms = fmaf(msc * msc, q, fmaf(2.f * msc, r1 * (1.f / 32.f), u1sq));
        mm2 = decay * decay * mm2 + 2.f * decay * omd * mmms + omd * omd * msms;

        y = fmaf(k1, y, omd * fmaf(msc, gxcol, ga * (1.f / 32.f)));

        const float inc1 = (l < NB) ? omd * alpha * (1.f / 32.f)
                                    : ((l == NB + t) ? omd * msc : 0.f);
        m1 = fmaf(k1, m1, inc1);
        m2 = fmaf(k1, m2, (t >= NB && l == t) ? omd * msc : 0.f);

        gxcol = gxn;
        xcol1 = xn1;
        xcol2 = xn2;
    }
}

__global__ __launch_bounds__(256) void foam_recon(
    const int* __restrict__ tokens, const float* __restrict__ E,
    const float* __restrict__ bubbles, float* __restrict__ ws)
{
    const int i = blockIdx.x;
    const int d = threadIdx.x;
    __shared__ float cfs[NBASIS];
    __shared__ int stok[SEQ];

    float val;
    if (i < NB) {
        val = bubbles[i * D + d];
    } else {
        const int t = i - NB;
        if (d < NBASIS) cfs[d] = ws[WS_COEF + t * NBASIS + d];
        if (d < SEQ) stok[d] = tokens[d];
        __syncthreads();
        float acc = 0.f;
        #pragma unroll 8
        for (int bb = 0; bb < NB; ++bb) acc = fmaf(cfs[bb], bubbles[bb * D + d], acc);
        #pragma unroll 8
        for (int j = 0; j < SEQ; ++j) acc = fmaf(cfs[32 + j], E[(long)stok[j] * D + d], acc);
        val = acc;
    }
    short hi, lo;
    split1(val, hi, lo);
    unsigned short* Whl = (unsigned short*)(ws + WS_WHL);
    Whl[i * D + d]               = (unsigned short)hi;
    Whl[NBASIS * D + i * D + d]  = (unsigned short)lo;
}

#define HS 100
#define US 36

__global__ __launch_bounds__(512, 2) void foam_mfma_logits(
    const float* __restrict__ E,
    const float* __restrict__ ws,
    float* __restrict__ out)
{
    __shared__ short Ah[MROWS * AS];
    __shared__ short Al[MROWS * AS];
    __shared__ float H[MROWS][HS];
    __shared__ float us[SEQ * US];
    __shared__ float vs[SEQ * US];
    __shared__ float Cs[SEQ];

    const int tid = threadIdx.x;
    const int w = tid >> 6;
    const int l = tid & 63;
    const int lm = l & 15;
    const int lq = l >> 4;

    const long vb = (long)blockIdx.x * MROWS;

    {
        const float* src = E + vb * D;
        const int base = tid * 16;
        const int row = base >> 8;
        const int col = base & 255;
        float4 v0 = *(const float4*)(src + base);
        float4 v1 = *(const float4*)(src + base + 4);
        float4 v2 = *(const float4*)(src + base + 8);
        float4 v3 = *(const float4*)(src + base + 12);
        float f[16] = {v0.x,v0.y,v0.z,v0.w, v1.x,v1.y,v1.z,v1.w,
                       v2.x,v2.y,v2.z,v2.w, v3.x,v3.y,v3.z,v3.w};
        short8v h0, h1, l0, l1;
        #pragma unroll
        for (int j = 0; j < 8; ++j) { short hi, lo; split1(f[j], hi, lo); h0[j] = hi; l0[j] = lo; }
        #pragma unroll
        for (int j = 0; j < 8; ++j) { short hi, lo; split1(f[8+j], hi, lo); h1[j] = hi; l1[j] = lo; }
        *(short8v*)&Ah[row * AS + col]     = h0;
        *(short8v*)&Ah[row * AS + col + 8] = h1;
        *(short8v*)&Al[row * AS + col]     = l0;
        *(short8v*)&Al[row * AS + col + 8] = l1;
    }

    for (int i = tid; i < SEQ * NB; i += 512) {
        int t = i >> 5, bb = i & 31;
        us[t * US + bb] = ws[WS_U + i];
        vs[t * US + bb] = ws[WS_VV + i];
    }
    if (tid < SEQ) Cs[tid] = ws[WS_C + tid];
    __syncthreads();

    if (w < 6) {
        const int n = w * 16 + lm;
        const short* bh = (const short*)(ws + WS_WHL) + n * D + lq * 8;
        const short* bl = bh + NBASIS * D;
        const short* ar = &Ah[lm * AS + lq * 8];
        const short* al = &Al[lm * AS + lq * 8];

        f32x4 acc0 = {0.f,0.f,0.f,0.f}, acc1 = {0.f,0.f,0.f,0.f};

        #pragma unroll
        for (int ks = 0; ks < 8; ++ks) {
            const short8v bhi = *(const short8v*)(bh + ks * 32);
            const short8v blo = *(const short8v*)(bl + ks * 32);

            short8v ahi = *(const short8v*)(ar + ks * 32);
            short8v alo = *(const short8v*)(al + ks * 32);
            acc0 = __builtin_amdgcn_mfma_f32_16x16x32_bf16(ahi, bhi, acc0, 0, 0, 0);
            acc0 = __builtin_amdgcn_mfma_f32_16x16x32_bf16(ahi, blo, acc0, 0, 0, 0);
            acc0 = __builtin_amdgcn_mfma_f32_16x16x32_bf16(alo, bhi, acc0, 0, 0, 0);

            ahi = *(const short8v*)(ar + 16 * AS + ks * 32);
            alo = *(const short8v*)(al + 16 * AS + ks * 32);
            acc1 = __builtin_amdgcn_mfma_f32_16x16x32_bf16(ahi, bhi, acc1, 0, 0, 0);
            acc1 = __builtin_amdgcn_mfma_f32_16x16x32_bf16(ahi, blo, acc1, 0, 0, 0);
            acc1 = __builtin_amdgcn_mfma_f32_16x16x32_bf16(alo, bhi, acc1, 0, 0, 0);
        }
        #pragma unroll
        for (int r = 0; r < 4; ++r) {
            H[lq * 4 + r][w * 16 + lm]      = acc0[r];
            H[16 + lq * 4 + r][w * 16 + lm] = acc1[r];
        }
    }
    __syncthreads();

    const int t0 = w * 8 + lq;
    const int t1 = t0 + 4;
    const float c0 = Cs[t0], c1 = Cs[t1];

    #pragma unroll
    for (int mt = 0; mt < 2; ++mt) {
        const int row = mt * 16 + lm;
        float G[NB];
        #pragma unroll
        for (int i = 0; i < 8; ++i)
            *(float4*)&G[4 * i] = *(const float4*)&H[row][4 * i];

        float a0 = 0.f, b0 = 0.f, a1 = 0.f, b1 = 0.f;
        #pragma unroll
        for (int i = 0; i < 8; ++i) {
            float g0 = G[4*i], g1 = G[4*i+1], g2c = G[4*i+2], g3 = G[4*i+3];
            float q0 = g0*g0, q1 = g1*g1, q2 = g2c*g2c, q3 = g3*g3;
            float4 u0 = *(const float4*)&us[t0 * US + 4 * i];
            float4 v0 = *(const float4*)&vs[t0 * US + 4 * i];
            float4 u1 = *(const float4*)&us[t1 * US + 4 * i];
            float4 v1 = *(const float4*)&vs[t1 * US + 4 * i];
            a0 = fmaf(u0.x, q0, fmaf(u0.y, q1, fmaf(u0.z, q2, fmaf(u0.w, q3, a0))));
            b0 = fmaf(v0.x, g0, fmaf(v0.y, g1, fmaf(v0.z, g2c, fmaf(v0.w, g3, b0))));
            a1 = fmaf(u1.x, q0, fmaf(u1.y, q1, fmaf(u1.z, q2, fmaf(u1.w, q3, a1))));
            b1 = fmaf(v1.x, g0, fmaf(v1.y, g1, fmaf(v1.z, g2c, fmaf(v1.w, g3, b1))));
        }
        const float h0 = H[row][32 + t0];
        const float h1 = H[row][32 + t1];
        out[(long)t0 * VOCAB + vb + row] = fmaf(h0, b0, fmaf(h0 * h0, c0, a0));
        out[(long)t1 * VOCAB + vb + row] = fmaf(h1, b1, fmaf(h1 * h1, c1, a1));
    }
}

extern "C" void kernel_launch(void* const* d_in, const int* in_sizes, int n_in,
                              void* d_out, int out_size, void* d_ws, size_t ws_size,
                              hipStream_t stream) {
    const int*   tokens  = (const int*)d_in[0];
    const float* E       = (const float*)d_in[1];
    const float* bubbles = (const float*)d_in[2];
    const float* mdb     = (const float*)d_in[3];
    const float* ns      = (const float*)d_in[4];
    float* out = (float*)d_out;
    float* ws  = (float*)d_ws;

    const size_t need = ((size_t)WS_HF + (size_t)VOCAB * NBASIS) * sizeof(float);

    hipLaunchKernelGGL(foam_prep, dim3(NBASIS), dim3(256), 0, stream,
                       tokens, E, bubbles, ws);

    if (ws_size >= need) {
        // fast path: scan overlapped with scan-independent GEMM, MFMA epilogue
        hipLaunchKernelGGL(foam_fused, dim3(VOCAB / MROWS + 1), dim3(512), 0, stream,
                           E, mdb, ns, ws);
        hipLaunchKernelGGL(foam_epilogue_mfma, dim3(VOCAB / 64), dim3(256), 0, stream,
                           ws, out);
    } else {
        // fallback: verified round-11 pipeline
        hipLaunchKernelGGL(foam_scan5, dim3(1), dim3(64), 0, stream, mdb, ns, ws);
        hipLaunchKernelGGL(foam_recon, dim3(NBASIS), dim3(256), 0, stream,
                           tokens, E, bubbles, ws);
        hipLaunchKernelGGL(foam_mfma_logits, dim3(VOCAB / MROWS), dim3(512), 0, stream,
                           E, ws, out);
    }
}

// Round 18
// 91.569 us; speedup vs baseline: 21.7352x; 1.0009x over previous
//
#include <hip/hip_runtime.h>
#include <math.h>

#define VOCAB 32000
#define D 256
#define NB 32
#define NEQ 5
#define SEQ 64
#define NBASIS 96   // 32 bubbles + 64 token vectors

// ws layout (float offsets)
#define WS_S     0                          // [96][96] Gram of basis U=[B;X]
#define WS_COEF  (NBASIS*NBASIS)            // [SEQ][96] x_wm coefficients
#define WS_U     (WS_COEF + SEQ*NBASIS)     // [SEQ][NB]
#define WS_VV    (WS_U + SEQ*NB)            // [SEQ][NB]  (must stay right after WS_U)
#define WS_C     (WS_VV + SEQ*NB)           // [SEQ]
#define WS_WHL   (WS_C + SEQ)               // ushort[2][96][256]: basis hi plane, lo plane
#define WS_HF    (WS_WHL + NBASIS*D/2*2)    // [VOCAB][96] fp32 Hf = E @ U^T (fast path)

typedef __attribute__((ext_vector_type(8))) short short8v;
typedef __attribute__((ext_vector_type(4))) float f32x4;

// ---------------------------------------------------------------------------
// Fast cross-lane / math primitives
// ---------------------------------------------------------------------------
template <int CTRL>
__device__ __forceinline__ float dpp_add(float x) {
    int yi = __builtin_amdgcn_update_dpp(0, __float_as_int(x), CTRL, 0xF, 0xF, true);
    return x + __int_as_float(yi);
}
__device__ __forceinline__ float xor16_add(float x) {
    float a, b;
    asm("v_mov_b32 %0, %2\n\t"
        "v_mov_b32 %1, %2\n\t"
        "v_permlane16_swap_b32 %0, %1"
        : "=&v"(a), "=&v"(b) : "v"(x));
    return a + b;
}
__device__ __forceinline__ float xor32_add(float x) {
    float a, b;
    asm("v_mov_b32 %0, %2\n\t"
        "v_mov_b32 %1, %2\n\t"
        "v_permlane32_swap_b32 %0, %1"
        : "=&v"(a), "=&v"(b) : "v"(x));
    return a + b;
}
__device__ __forceinline__ float sum32h(float x) {
    x = dpp_add<0xB1>(x);    // xor 1
    x = dpp_add<0x4E>(x);    // xor 2
    x = dpp_add<0x124>(x);   // row_ror:4
    x = dpp_add<0x128>(x);   // row_ror:8
    return xor16_add(x);
}
__device__ __forceinline__ float sum64(float x) {
    return xor32_add(sum32h(x));
}
__device__ __forceinline__ float rdlane(float v, int lane) {
    return __int_as_float(__builtin_amdgcn_readlane(__float_as_int(v), lane));
}
__device__ __forceinline__ float fast_rcp(float x) {
    float r; asm("v_rcp_f32 %0, %1" : "=v"(r) : "v"(x)); return r;
}
__device__ __forceinline__ float fast_sqrt(float x) {
    float r; asm("v_sqrt_f32 %0, %1" : "=v"(r) : "v"(x)); return r;
}
__device__ __forceinline__ float fast_exp2(float x) {
    float r; asm("v_exp_f32 %0, %1" : "=v"(r) : "v"(x)); return r;
}
__device__ __forceinline__ void split1(float x, short& hi, short& lo) {
    unsigned xb = __builtin_bit_cast(unsigned, x);
    unsigned hb = xb & 0xFFFF0000u;
    float fl = x - __builtin_bit_cast(float, hb);
    hi = (short)(hb >> 16);
    lo = (short)(__builtin_bit_cast(unsigned, fl) >> 16);
}
// split 8 f32 (from memory) -> bf16 hi/lo fragments
__device__ __forceinline__ void split_bf16(const float* p, short8v& hi, short8v& lo) {
    float4 f0 = *(const float4*)p;
    float4 f1 = *(const float4*)(p + 4);
    float f[8] = {f0.x, f0.y, f0.z, f0.w, f1.x, f1.y, f1.z, f1.w};
    #pragma unroll
    for (int j = 0; j < 8; ++j) { short h, l; split1(f[j], h, l); hi[j] = h; lo[j] = l; }
}
// split 8 f32 (register array) -> bf16 hi/lo fragments
__device__ __forceinline__ void split8r(const float* f, short8v& hi, short8v& lo) {
    #pragma unroll
    for (int j = 0; j < 8; ++j) { short h, l; split1(f[j], h, l); hi[j] = h; lo[j] = l; }
}

// ---------------------------------------------------------------------------
// K1: Gram matrix + U bf16 hi/lo planes (U = [bubbles; E[tokens]]).
// ---------------------------------------------------------------------------
__global__ __launch_bounds__(256) void foam_prep(
    const int* __restrict__ tokens, const float* __restrict__ E,
    const float* __restrict__ bubbles, float* __restrict__ ws)
{
    const int bid = blockIdx.x;    // basis row 0..95
    const int d = threadIdx.x;

    {
        const float val = (bid < NB) ? bubbles[bid * D + d]
                                     : E[(long)tokens[bid - NB] * D + d];
        short hi, lo;
        split1(val, hi, lo);
        unsigned short* Uhl = (unsigned short*)(ws + WS_WHL);
        Uhl[bid * D + d]              = (unsigned short)hi;
        Uhl[NBASIS * D + bid * D + d] = (unsigned short)lo;
    }

    const int idx = bid * 256 + d;
    if (idx < NBASIS * NBASIS) {
        const int i = idx / NBASIS, j = idx % NBASIS;
        const float4* ra = (const float4*)((i < NB) ? (bubbles + i * D)
                                                    : (E + (long)tokens[i - NB] * D));
        const float4* rb = (const float4*)((j < NB) ? (bubbles + j * D)
                                                    : (E + (long)tokens[j - NB] * D));
        float a0 = 0.f, a1 = 0.f, a2 = 0.f, a3 = 0.f;
        #pragma unroll
        for (int k = 0; k < D / 4; k += 4) {
            float4 x, y;
            x = ra[k];     y = rb[k];
            a0 = fmaf(x.x, y.x, fmaf(x.y, y.y, fmaf(x.z, y.z, fmaf(x.w, y.w, a0))));
            x = ra[k + 1]; y = rb[k + 1];
            a1 = fmaf(x.x, y.x, fmaf(x.y, y.y, fmaf(x.z, y.z, fmaf(x.w, y.w, a1))));
            x = ra[k + 2]; y = rb[k + 2];
            a2 = fmaf(x.x, y.x, fmaf(x.y, y.y, fmaf(x.z, y.z, fmaf(x.w, y.w, a2))));
            x = ra[k + 3]; y = rb[k + 3];
            a3 = fmaf(x.x, y.x, fmaf(x.y, y.y, fmaf(x.z, y.z, fmaf(x.w, y.w, a3))));
        }
        ws[WS_S + i * NBASIS + j] = (a0 + a1) + (a2 + a3);
    }
}

// ---------------------------------------------------------------------------
// KF: fused kernel. Block 0 = serial scan; blocks 1..1000 = GEMM Hf = E @ U^T.
// __launch_bounds__(512,4): VGPR cap 128 so the scan branch's gbb_row[32] +
// asg[32] stay in registers (at (512) default the cap is 64 -> scratch spill
// on the serial critical path; fused showed VGPR=48 vs standalone scan's 88).
// GEMM blocks drop to 2/CU but remain hidden under the ~60us scan.
// ---------------------------------------------------------------------------
#define MROWS 32
#define AS 264    // LDS A row stride in bf16 elems

__global__ __launch_bounds__(512, 4) void foam_fused(
    const float* __restrict__ E,
    const float* __restrict__ p_mdb, const float* __restrict__ p_ns,
    float* __restrict__ ws)
{
    __shared__ __align__(16) char smem[MROWS * AS * 2 * 2];   // 33792 B
    const int tid = threadIdx.x;

    if (blockIdx.x == 0) {
        // ================= scan (verified round-9/11 body) =================
        float (*S2)[NBASIS] = (float (*)[NBASIS])smem;
        const int l = tid;
        const int b = l & 31;
        const float* wsS = ws + WS_S;

        for (int e = l; e < SEQ * NBASIS / 4; e += 64)
            ((float4*)S2)[e] = ((const float4*)(wsS + NB * NBASIS))[e];

        float gbb_row[NB];
        {
            const float4* pa = (const float4*)(wsS + b * NBASIS);
            #pragma unroll
            for (int i = 0; i < 8; ++i) {
                float4 va = pa[i];
                gbb_row[4*i] = va.x; gbb_row[4*i+1] = va.y;
                gbb_row[4*i+2] = va.z; gbb_row[4*i+3] = va.w;
            }
        }
        const float diag = wsS[(NB + (l & 63)) * NBASIS + NB + (l & 63)];
        const float bn2  = wsS[b * NBASIS + b];

        const float LOG2E = 1.44269504088896f;
        const float mdb2  = p_mdb[0] * LOG2E;
        const float sens2 = fabsf(p_ns[0]) * LOG2E;
        const float sl2e  = 0.0625f * LOG2E;

        __syncthreads();
        if (l >= 64) return;

        float y = 0.f, mm2 = 0.f;
        float m1 = 0.f, m2 = 0.f;

        float* wsCOEF = ws + WS_COEF;
        float* wsUV   = ws + WS_U;
        float* wsC    = ws + WS_C;

        float gxcol = S2[0][b];
        float xcol1 = S2[0][l];
        float xcol2 = S2[0][32 + l];

        const int uvoff = (l >> 5) * (SEQ * NB);

        #pragma unroll 4
        for (int t = 0; t < SEQ; ++t) {
            const float xdm = sum64(fmaf(xcol2, m2, xcol1 * m1));
            const float px  = rdlane(diag, t);
            const float nov = (mm2 > 9.8e-17f)
                            ? (1.f - xdm * fast_rcp(fast_sqrt(px * mm2)))
                            : 1.f;
            const float decay = fast_rcp(1.f + fast_exp2(fmaf(sens2, nov, -mdb2)));
            const float omd = 1.f - decay;

            wsCOEF[t * NBASIS + l] = fmaf(decay, m1, (l == NB + t) ? 1.f : 0.f);
            if (l >= 32)
                wsCOEF[t * NBASIS + 32 + l] = fmaf(decay, m2, (l == t) ? 1.f : 0.f);

            const float q = px + 2.f * decay * xdm + decay * decay * mm2;
            const float c = fmaf(decay, y, gxcol);

            const int tn = (t + 1) & (SEQ - 1);
            const float gxn = S2[tn][b];
            const float xn1 = S2[tn][l];
            const float xn2 = S2[tn][32 + l];

            const float cq2 = (c - q) * sl2e;
            float alpha = 1.f, p = 0.f;
            #pragma unroll
            for (int k = 0; k <= NEQ; ++k) {
                const float ev = fast_exp2(alpha * cq2);
                const float sm = sum32h(ev);
                const float r  = fast_rcp(sm);
                if (k < NEQ) {
                    const float ae = alpha * ev;
                    alpha = fmaf(-ae, r, alpha);
                } else {
                    p = ev * r;
                }
            }

            const float oma = 1.f - alpha;
            const float s2v = alpha * alpha * bn2 + 2.f * alpha * oma * c + oma * oma * q;
            const float g = p * fast_rcp(s2v + 1e-20f);
            const float uu  = g * alpha * alpha;
            const float vv2 = 2.f * g * alpha * oma;
            wsUV[uvoff + t * NB + b] = (l < NB) ? uu : vv2;

            float asg[NB];
            #pragma unroll
            for (int j = 0; j < NB; ++j) asg[j] = rdlane(alpha, j);
            float ga0 = 0.f, ga1 = 0.f, ga2 = 0.f, ga3 = 0.f;
            #pragma unroll
            for (int j = 0; j < NB; j += 4) {
                ga0 = fmaf(gbb_row[j],     asg[j],     ga0);
                ga1 = fmaf(gbb_row[j + 1], asg[j + 1], ga1);
                ga2 = fmaf(gbb_row[j + 2], asg[j + 2], ga2);
                ga3 = fmaf(gbb_row[j + 3], asg[j + 3], ga3);
            }
            const float ga = (ga0 + ga1) + (ga2 + ga3);

            const float r0 = sum32h(alpha);
            const float r1 = sum32h(alpha * c);
            const float r2 = sum32h(alpha * y);
            const float r3 = sum32h(alpha * ga);
            const float Cp = sum32h(g * oma * oma);
            if (l == 0) wsC[t] = Cp;

            const float msc = (32.f - r0) * (1.f / 32.f);
            const float k1 = decay * fmaf(omd, msc, 1.f);
            const float mmxwm = fmaf(decay, mm2, xdm);
            const float mmms = fmaf(msc, mmxwm, r2 * (1.f / 32.f));
            const float u1sq = r3 * (1.f / 1024.f);
            const float msms = fmaf(msc * msc, q, fmaf(2.f * msc, r1 * (1.f / 32.f), u1sq));
            mm2 = decay * decay * mm2 + 2.f * decay * omd * mmms + omd * omd * msms;

            y = fmaf(k1, y, omd * fmaf(msc, gxcol, ga * (1.f / 32.f)));

            const float inc1 = (l < NB) ? omd * alpha * (1.f / 32.f)
                                        : ((l == NB + t) ? omd * msc : 0.f);
            m1 = fmaf(k1, m1, inc1);
            m2 = fmaf(k1, m2, (t >= NB && l == t) ? omd * msc : 0.f);

            gxcol = gxn;
            xcol1 = xn1;
            xcol2 = xn2;
        }
        return;
    }

    // ================= GEMM blocks: Hf = E @ U^T =================
    short* Ah = (short*)smem;
    short* Al = Ah + MROWS * AS;

    const int w = tid >> 6;
    const int l = tid & 63;
    const int lm = l & 15;
    const int lq = l >> 4;

    const long vb = (long)(blockIdx.x - 1) * MROWS;

    {
        const float* src = E + vb * D;
        const int base = tid * 16;
        const int row = base >> 8;
        const int col = base & 255;
        float4 v0 = *(const float4*)(src + base);
        float4 v1 = *(const float4*)(src + base + 4);
        float4 v2 = *(const float4*)(src + base + 8);
        float4 v3 = *(const float4*)(src + base + 12);
        float f[16] = {v0.x,v0.y,v0.z,v0.w, v1.x,v1.y,v1.z,v1.w,
                       v2.x,v2.y,v2.z,v2.w, v3.x,v3.y,v3.z,v3.w};
        short8v h0, h1, l0, l1;
        #pragma unroll
        for (int j = 0; j < 8; ++j) { short hi, lo; split1(f[j], hi, lo); h0[j] = hi; l0[j] = lo; }
        #pragma unroll
        for (int j = 0; j < 8; ++j) { short hi, lo; split1(f[8+j], hi, lo); h1[j] = hi; l1[j] = lo; }
        *(short8v*)&Ah[row * AS + col]     = h0;
        *(short8v*)&Ah[row * AS + col + 8] = h1;
        *(short8v*)&Al[row * AS + col]     = l0;
        *(short8v*)&Al[row * AS + col + 8] = l1;
    }
    __syncthreads();

    if (w >= 6) return;

    const int n = w * 16 + lm;
    const short* bh = (const short*)(ws + WS_WHL) + n * D + lq * 8;
    const short* bl = bh + NBASIS * D;
    const short* ar = &Ah[lm * AS + lq * 8];
    const short* al = &Al[lm * AS + lq * 8];

    f32x4 acc0 = {0.f,0.f,0.f,0.f}, acc1 = {0.f,0.f,0.f,0.f};

    #pragma unroll
    for (int ks = 0; ks < 8; ++ks) {
        const short8v bhi = *(const short8v*)(bh + ks * 32);
        const short8v blo = *(const short8v*)(bl + ks * 32);

        short8v ahi = *(const short8v*)(ar + ks * 32);
        short8v alo = *(const short8v*)(al + ks * 32);
        acc0 = __builtin_amdgcn_mfma_f32_16x16x32_bf16(ahi, bhi, acc0, 0, 0, 0);
        acc0 = __builtin_amdgcn_mfma_f32_16x16x32_bf16(ahi, blo, acc0, 0, 0, 0);
        acc0 = __builtin_amdgcn_mfma_f32_16x16x32_bf16(alo, bhi, acc0, 0, 0, 0);

        ahi = *(const short8v*)(ar + 16 * AS + ks * 32);
        alo = *(const short8v*)(al + 16 * AS + ks * 32);
        acc1 = __builtin_amdgcn_mfma_f32_16x16x32_bf16(ahi, bhi, acc1, 0, 0, 0);
        acc1 = __builtin_amdgcn_mfma_f32_16x16x32_bf16(ahi, blo, acc1, 0, 0, 0);
        acc1 = __builtin_amdgcn_mfma_f32_16x16x32_bf16(alo, bhi, acc1, 0, 0, 0);
    }

    float* Hf = ws + WS_HF;
    #pragma unroll
    for (int r = 0; r < 4; ++r) {
        Hf[(vb + lq * 4 + r) * NBASIS + w * 16 + lm]      = acc0[r];
        Hf[(vb + 16 + lq * 4 + r) * NBASIS + w * 16 + lm] = acc1[r];
    }
}

// ---------------------------------------------------------------------------
// KE: MFMA epilogue. Three small GEMMs + combine, zero LDS.
//   h = Hf @ coef^T, a = G2 @ us^T, b = G @ vs^T;  out = a + h*b + h^2*C[t].
// ---------------------------------------------------------------------------
__global__ __launch_bounds__(256) void foam_epilogue_mfma(
    const float* __restrict__ ws, float* __restrict__ out)
{
    const int tid = threadIdx.x;
    const int w = tid >> 6;        // wave -> token tile
    const int l = tid & 63;
    const int lm = l & 15;
    const int lq = l >> 4;

    const int t = w * 16 + lm;     // A-operand row (token)

    // A fragments (persistent): coef 3 ksteps, us/vs 1 kstep
    short8v Ch0, Cl0, Ch1, Cl1, Ch2, Cl2, Uh, Ul, Vh, Vl;
    split_bf16(ws + WS_COEF + t * NBASIS + lq * 8,      Ch0, Cl0);
    split_bf16(ws + WS_COEF + t * NBASIS + 32 + lq * 8, Ch1, Cl1);
    split_bf16(ws + WS_COEF + t * NBASIS + 64 + lq * 8, Ch2, Cl2);
    split_bf16(ws + WS_U  + t * NB + lq * 8, Uh, Ul);
    split_bf16(ws + WS_VV + t * NB + lq * 8, Vh, Vl);

    float Cr[4];
    #pragma unroll
    for (int r = 0; r < 4; ++r) Cr[r] = ws[WS_C + w * 16 + lq * 4 + r];

    const long VB = (long)blockIdx.x * 64;

    #pragma unroll
    for (int n = 0; n < 4; ++n) {
        const long v = VB + n * 16 + lm;              // B-operand col (vocab)
        const float* hrow = ws + WS_HF + v * NBASIS + lq * 8;

        // kstep 0: keep G (split Hf) and G2 (split Hf^2)
        float4 fa = *(const float4*)hrow;
        float4 fb = *(const float4*)(hrow + 4);
        float f0[8] = {fa.x, fa.y, fa.z, fa.w, fb.x, fb.y, fb.z, fb.w};
        short8v Bh0, Bl0, Qh, Ql;
        split8r(f0, Bh0, Bl0);
        float g2[8];
        #pragma unroll
        for (int j = 0; j < 8; ++j) g2[j] = f0[j] * f0[j];
        split8r(g2, Qh, Ql);

        f32x4 ah = {0.f,0.f,0.f,0.f}, aa = {0.f,0.f,0.f,0.f}, ab = {0.f,0.f,0.f,0.f};

        ah = __builtin_amdgcn_mfma_f32_16x16x32_bf16(Ch0, Bh0, ah, 0, 0, 0);
        ah = __builtin_amdgcn_mfma_f32_16x16x32_bf16(Ch0, Bl0, ah, 0, 0, 0);
        ah = __builtin_amdgcn_mfma_f32_16x16x32_bf16(Cl0, Bh0, ah, 0, 0, 0);

        aa = __builtin_amdgcn_mfma_f32_16x16x32_bf16(Uh, Qh, aa, 0, 0, 0);
        aa = __builtin_amdgcn_mfma_f32_16x16x32_bf16(Uh, Ql, aa, 0, 0, 0);
        aa = __builtin_amdgcn_mfma_f32_16x16x32_bf16(Ul, Qh, aa, 0, 0, 0);

        ab = __builtin_amdgcn_mfma_f32_16x16x32_bf16(Vh, Bh0, ab, 0, 0, 0);
        ab = __builtin_amdgcn_mfma_f32_16x16x32_bf16(Vh, Bl0, ab, 0, 0, 0);
        ab = __builtin_amdgcn_mfma_f32_16x16x32_bf16(Vl, Bh0, ab, 0, 0, 0);

        // ksteps 1,2 of h
        short8v Bh, Bl;
        split_bf16(hrow + 32, Bh, Bl);
        ah = __builtin_amdgcn_mfma_f32_16x16x32_bf16(Ch1, Bh, ah, 0, 0, 0);
        ah = __builtin_amdgcn_mfma_f32_16x16x32_bf16(Ch1, Bl, ah, 0, 0, 0);
        ah = __builtin_amdgcn_mfma_f32_16x16x32_bf16(Cl1, Bh, ah, 0, 0, 0);

        split_bf16(hrow + 64, Bh, Bl);
        ah = __builtin_amdgcn_mfma_f32_16x16x32_bf16(Ch2, Bh, ah, 0, 0, 0);
        ah = __builtin_amdgcn_mfma_f32_16x16x32_bf16(Ch2, Bl, ah, 0, 0, 0);
        ah = __builtin_amdgcn_mfma_f32_16x16x32_bf16(Cl2, Bh, ah, 0, 0, 0);

        // combine + store: D row = token (lq*4+r), col = vocab (lm)
        #pragma unroll
        for (int r = 0; r < 4; ++r) {
            const float h = ah[r];
            out[(long)(w * 16 + lq * 4 + r) * VOCAB + VB + n * 16 + lm] =
                fmaf(h, ab[r], fmaf(h * h, Cr[r], aa[r]));
        }
    }
}

// ===========================================================================
// Fallback path (verified round-11), used when ws is too small for Hf.
// ===========================================================================
__global__ __launch_bounds__(64) void foam_scan5(
    const float* __restrict__ p_mdb, const float* __restrict__ p_ns,
    float* __restrict__ ws)
{
    const int l = threadIdx.x;
    const int b = l & 31;

    __shared__ float S2[SEQ][NBASIS];

    const float* wsS = ws + WS_S;
    for (int e = l; e < SEQ * NBASIS / 4; e += 64)
        ((float4*)S2)[e] = ((const float4*)(wsS + NB * NBASIS))[e];

    float gbb_row[NB];
    {
        const float4* pa = (const float4*)(wsS + b * NBASIS);
        #pragma unroll
        for (int i = 0; i < 8; ++i) {
            float4 va = pa[i];
            gbb_row[4*i] = va.x; gbb_row[4*i+1] = va.y;
            gbb_row[4*i+2] = va.z; gbb_row[4*i+3] = va.w;
        }
    }
    const float diag = wsS[(NB + l) * NBASIS + NB + l];
    const float bn2  = wsS[b * NBASIS + b];

    const float LOG2E = 1.44269504088896f;
    const float mdb2  = p_mdb[0] * LOG2E;
    const float sens2 = fabsf(p_ns[0]) * LOG2E;
    const float sl2e  = 0.0625f * LOG2E;

    __syncthreads();

    float y = 0.f, mm2 = 0.f;
    float m1 = 0.f, m2 = 0.f;

    float* wsCOEF = ws + WS_COEF;
    float* wsUV   = ws + WS_U;
    float* wsC    = ws + WS_C;

    float gxcol = S2[0][b];
    float xcol1 = S2[0][l];
    float xcol2 = S2[0][32 + l];

    const int uvoff = (l >> 5) * (SEQ * NB);

    #pragma unroll 4
    for (int t = 0; t < SEQ; ++t) {
        const float xdm = sum64(fmaf(xcol2, m2, xcol1 * m1));
        const float px  = rdlane(diag, t);
        const float nov = (mm2 > 9.8e-17f)
                        ? (1.f - xdm * fast_rcp(fast_sqrt(px * mm2)))
                        : 1.f;
        const float decay = fast_rcp(1.f + fast_exp2(fmaf(sens2, nov, -mdb2)));
        const float omd = 1.f - decay;

        wsCOEF[t * NBASIS + l] = fmaf(decay, m1, (l == NB + t) ? 1.f : 0.f);
        if (l >= 32)
            wsCOEF[t * NBASIS + 32 + l] = fmaf(decay, m2, (l == t) ? 1.f : 0.f);

        const float q = px + 2.f * decay * xdm + decay * decay * mm2;
        const float c = fmaf(decay, y, gxcol);

        const int tn = (t + 1) & (SEQ - 1);
        const float gxn = S2[tn][b];
        const float xn1 = S2[tn][l];
        const float xn2 = S2[tn][32 + l];

        const float cq2 = (c - q) * sl2e;
        float alpha = 1.f, p = 0.f;
        #pragma unroll
        for (int k = 0; k <= NEQ; ++k) {
            const float ev = fast_exp2(alpha * cq2);
            const float sm = sum32h(ev);
            const float r  = fast_rcp(sm);
            if (k < NEQ) {
                const float ae = alpha * ev;
                alpha = fmaf(-ae, r, alpha);
            } else {
                p = ev * r;
            }
        }

        const float oma = 1.f - alpha;
        const float s2v = alpha * alpha * bn2 + 2.f * alpha * oma * c + oma * oma * q;
        const float g = p * fast_rcp(s2v + 1e-20f);
        const float uu  = g * alpha * alpha;
        const float vv2 = 2.f * g * alpha * oma;
        wsUV[uvoff + t * NB + b] = (l < NB) ? uu : vv2;

        float asg[NB];
        #pragma unroll
        for (int j = 0; j < NB; ++j) asg[j] = rdlane(alpha, j);
        float ga0 = 0.f, ga1 = 0.f, ga2 = 0.f, ga3 = 0.f;
        #pragma unroll
        for (int j = 0; j < NB; j += 4) {
            ga0 = fmaf(gbb_row[j],     asg[j],     ga0);
            ga1 = fmaf(gbb_row[j + 1], asg[j + 1], ga1);
            ga2 = fmaf(gbb_row[j + 2], asg[j + 2], ga2);
            ga3 = fmaf(gbb_row[j + 3], asg[j + 3], ga3);
        }
        const float ga = (ga0 + ga1) + (ga2 + ga3);

        const float r0 = sum32h(alpha);
        const float r1 = sum32h(alpha * c);
        const float r2 = sum32h(alpha * y);
        const float r3 = sum32h(alpha * ga);
        const float Cp = sum32h(g * oma * oma);
        if (l == 0) wsC[t] = Cp;

        const float msc = (32.f - r0) * (1.f / 32.f);
        const float k1 = decay * fmaf(omd, msc, 1.f);
        const float mmxwm = fmaf(decay, mm2, xdm);
        const float mmms = fmaf(msc, mmxwm, r2 * (1.f / 32.f));
        const float u1sq = r3 * (1.f / 1024.f);
        const float msms = fmaf(msc * msc, q, fmaf(2.f * msc, r1 * (1.f / 32.f), u1sq));
        mm2 = decay * decay * mm2 + 2.f * decay * omd * mmms + omd * omd * msms;

        y = fmaf(k1, y, omd * fmaf(msc, gxcol, ga * (1.f / 32.f)));

        const float inc1 = (l < NB) ? omd * alpha * (1.f / 32.f)
                                    : ((l == NB + t) ? omd * msc : 0.f);
        m1 = fmaf(k1, m1, inc1);
        m2 = fmaf(k1, m2, (t >= NB && l == t) ? omd * msc : 0.f);

        gxcol = gxn;
        xcol1 = xn1;
        xcol2 = xn2;
    }
}

__global__ __launch_bounds__(256) void foam_recon(
    const int* __restrict__ tokens, const float* __restrict__ E,
    const float* __restrict__ bubbles, float* __restrict__ ws)
{
    const int i = blockIdx.x;
    const int d = threadIdx.x;
    __shared__ float cfs[NBASIS];
    __shared__ int stok[SEQ];

    float val;
    if (i < NB) {
        val = bubbles[i * D + d];
    } else {
        const int t = i - NB;
        if (d < NBASIS) cfs[d] = ws[WS_COEF + t * NBASIS + d];
        if (d < SEQ) stok[d] = tokens[d];
        __syncthreads();
        float acc = 0.f;
        #pragma unroll 8
        for (int bb = 0; bb < NB; ++bb) acc = fmaf(cfs[bb], bubbles[bb * D + d], acc);
        #pragma unroll 8
        for (int j = 0; j < SEQ; ++j) acc = fmaf(cfs[32 + j], E[(long)stok[j] * D + d], acc);
        val = acc;
    }
    short hi, lo;
    split1(val, hi, lo);
    unsigned short* Whl = (unsigned short*)(ws + WS_WHL);
    Whl[i * D + d]               = (unsigned short)hi;
    Whl[NBASIS * D + i * D + d]  = (unsigned short)lo;
}

#define HS 100
#define US 36

__global__ __launch_bounds__(512, 2) void foam_mfma_logits(
    const float* __restrict__ E,
    const float* __restrict__ ws,
    float* __restrict__ out)
{
    __shared__ short Ah[MROWS * AS];
    __shared__ short Al[MROWS * AS];
    __shared__ float H[MROWS][HS];
    __shared__ float us[SEQ * US];
    __shared__ float vs[SEQ * US];
    __shared__ float Cs[SEQ];

    const int tid = threadIdx.x;
    const int w = tid >> 6;
    const int l = tid & 63;
    const int lm = l & 15;
    const int lq = l >> 4;

    const long vb = (long)blockIdx.x * MROWS;

    {
        const float* src = E + vb * D;
        const int base = tid * 16;
        const int row = base >> 8;
        const int col = base & 255;
        float4 v0 = *(const float4*)(src + base);
        float4 v1 = *(const float4*)(src + base + 4);
        float4 v2 = *(const float4*)(src + base + 8);
        float4 v3 = *(const float4*)(src + base + 12);
        float f[16] = {v0.x,v0.y,v0.z,v0.w, v1.x,v1.y,v1.z,v1.w,
                       v2.x,v2.y,v2.z,v2.w, v3.x,v3.y,v3.z,v3.w};
        short8v h0, h1, l0, l1;
        #pragma unroll
        for (int j = 0; j < 8; ++j) { short hi, lo; split1(f[j], hi, lo); h0[j] = hi; l0[j] = lo; }
        #pragma unroll
        for (int j = 0; j < 8; ++j) { short hi, lo; split1(f[8+j], hi, lo); h1[j] = hi; l1[j] = lo; }
        *(short8v*)&Ah[row * AS + col]     = h0;
        *(short8v*)&Ah[row * AS + col + 8] = h1;
        *(short8v*)&Al[row * AS + col]     = l0;
        *(short8v*)&Al[row * AS + col + 8] = l1;
    }

    for (int i = tid; i < SEQ * NB; i += 512) {
        int t = i >> 5, bb = i & 31;
        us[t * US + bb] = ws[WS_U + i];
        vs[t * US + bb] = ws[WS_VV + i];
    }
    if (tid < SEQ) Cs[tid] = ws[WS_C + tid];
    __syncthreads();

    if (w < 6) {
        const int n = w * 16 + lm;
        const short* bh = (const short*)(ws + WS_WHL) + n * D + lq * 8;
        const short* bl = bh + NBASIS * D;
        const short* ar = &Ah[lm * AS + lq * 8];
        const short* al = &Al[lm * AS + lq * 8];

        f32x4 acc0 = {0.f,0.f,0.f,0.f}, acc1 = {0.f,0.f,0.f,0.f};

        #pragma unroll
        for (int ks = 0; ks < 8; ++ks) {
            const short8v bhi = *(const short8v*)(bh + ks * 32);
            const short8v blo = *(const short8v*)(bl + ks * 32);

            short8v ahi = *(const short8v*)(ar + ks * 32);
            short8v alo = *(const short8v*)(al + ks * 32);
            acc0 = __builtin_amdgcn_mfma_f32_16x16x32_bf16(ahi, bhi, acc0, 0, 0, 0);
            acc0 = __builtin_amdgcn_mfma_f32_16x16x32_bf16(ahi, blo, acc0, 0, 0, 0);
            acc0 = __builtin_amdgcn_mfma_f32_16x16x32_bf16(alo, bhi, acc0, 0, 0, 0);

            ahi = *(const short8v*)(ar + 16 * AS + ks * 32);
            alo = *(const short8v*)(al + 16 * AS + ks * 32);
            acc1 = __builtin_amdgcn_mfma_f32_16x16x32_bf16(ahi, bhi, acc1, 0, 0, 0);
            acc1 = __builtin_amdgcn_mfma_f32_16x16x32_bf16(ahi, blo, acc1, 0, 0, 0);
            acc1 = __builtin_amdgcn_mfma_f32_16x16x32_bf16(alo, bhi, acc1, 0, 0, 0);
        }
        #pragma unroll
        for (int r = 0; r < 4; ++r) {
            H[lq * 4 + r][w * 16 + lm]      = acc0[r];
            H[16 + lq * 4 + r][w * 16 + lm] = acc1[r];
        }
    }
    __syncthreads();

    const int t0 = w * 8 + lq;
    const int t1 = t0 + 4;
    const float c0 = Cs[t0], c1 = Cs[t1];

    #pragma unroll
    for (int mt = 0; mt < 2; ++mt) {
        const int row = mt * 16 + lm;
        float G[NB];
        #pragma unroll
        for (int i = 0; i < 8; ++i)
            *(float4*)&G[4 * i] = *(const float4*)&H[row][4 * i];

        float a0 = 0.f, b0 = 0.f, a1 = 0.f, b1 = 0.f;
        #pragma unroll
        for (int i = 0; i < 8; ++i) {
            float g0 = G[4*i], g1 = G[4*i+1], g2c = G[4*i+2], g3 = G[4*i+3];
            float q0 = g0*g0, q1 = g1*g1, q2 = g2c*g2c, q3 = g3*g3;
            float4 u0 = *(const float4*)&us[t0 * US + 4 * i];
            float4 v0 = *(const float4*)&vs[t0 * US + 4 * i];
            float4 u1 = *(const float4*)&us[t1 * US + 4 * i];
            float4 v1 = *(const float4*)&vs[t1 * US + 4 * i];
            a0 = fmaf(u0.x, q0, fmaf(u0.y, q1, fmaf(u0.z, q2, fmaf(u0.w, q3, a0))));
            b0 = fmaf(v0.x, g0, fmaf(v0.y, g1, fmaf(v0.z, g2c, fmaf(v0.w, g3, b0))));
            a1 = fmaf(u1.x, q0, fmaf(u1.y, q1, fmaf(u1.z, q2, fmaf(u1.w, q3, a1))));
            b1 = fmaf(v1.x, g0, fmaf(v1.y, g1, fmaf(v1.z, g2c, fmaf(v1.w, g3, b1))));
        }
        const float h0 = H[row][32 + t0];
        const float h1 = H[row][32 + t1];
        out[(long)t0 * VOCAB + vb + row] = fmaf(h0, b0, fmaf(h0 * h0, c0, a0));
        out[(long)t1 * VOCAB + vb + row] = fmaf(h1, b1, fmaf(h1 * h1, c1, a1));
    }
}

extern "C" void kernel_launch(void* const* d_in, const int* in_sizes, int n_in,
                              void* d_out, int out_size, void* d_ws, size_t ws_size,
                              hipStream_t stream) {
    const int*   tokens  = (const int*)d_in[0];
    const float* E       = (const float*)d_in[1];
    const float* bubbles = (const float*)d_in[2];
    const float* mdb     = (const float*)d_in[3];
    const float* ns      = (const float*)d_in[4];
    float* out = (float*)d_out;
    float* ws  = (float*)d_ws;

    const size_t need = ((size_t)WS_HF + (size_t)VOCAB * NBASIS) * sizeof(float);

    hipLaunchKernelGGL(foam_prep, dim3(NBASIS), dim3(256), 0, stream,
                       tokens, E, bubbles, ws);

    if (ws_size >= need) {
        // fast path: scan overlapped with scan-independent GEMM, MFMA epilogue
        hipLaunchKernelGGL(foam_fused, dim3(VOCAB / MROWS + 1), dim3(512), 0, stream,
                           E, mdb, ns, ws);
        hipLaunchKernelGGL(foam_epilogue_mfma, dim3(VOCAB / 64), dim3(256), 0, stream,
                           ws, out);
    } else {
        // fallback: verified round-11 pipeline
        hipLaunchKernelGGL(foam_scan5, dim3(1), dim3(64), 0, stream, mdb, ns, ws);
        hipLaunchKernelGGL(foam_recon, dim3(NBASIS), dim3(256), 0, stream,
                           tokens, E, bubbles, ws);
        hipLaunchKernelGGL(foam_mfma_logits, dim3(VOCAB / MROWS), dim3(512), 0, stream,
                           E, ws, out);
    }
}